// Round 4
// baseline (420.993 us; speedup 1.0000x reference)
//
#include <hip/hip_runtime.h>
#include <math.h>

// Problem constants
#define LQ    512
#define DS    384
#define DPAIR 128
#define NH    12
#define NPP   1792   // padded projection width
#define TJC   64     // j-chunk for pair kernel
#define NC    8      // number of j-chunks (LQ/TJC)

typedef unsigned short u16;
typedef unsigned int   u32;
typedef __attribute__((ext_vector_type(8))) short bf16x8;  // 8 bf16 in 4 VGPRs
typedef __attribute__((ext_vector_type(4))) float f32x4;

// round-to-nearest-even f32 -> bf16 bits
__device__ inline u16 bf16_rne(float x) {
  u32 u = __float_as_uint(x);
  u32 r = (u + 0x7FFFu + ((u >> 16) & 1u)) >> 16;
  return (u16)r;
}
// split x ~= hi + lo (both bf16); residual ~2^-17 relative
__device__ inline void split_bf16(float x, u16& h, u16& l) {
  u16 hb = bf16_rne(x);
  float hf = __uint_as_float(((u32)hb) << 16);
  h = hb;
  l = bf16_rne(x - hf);
}

// ---------------------------------------------------------------- fused prep:
// blocks 0..167   : Wcat transpose+split tiles -> WcatT [NPP][DS] bf16 hi/lo
// block  168      : bcat + WpbT
// blocks 169..384 : Wo transpose+split tiles   -> WoT [384][2304] bf16 hi/lo
// blocks 385..896 : layernorm rows -> sn split-bf16
__global__ __launch_bounds__(256) void k_prep(
    const float* __restrict__ Wq, const float* __restrict__ Wk,
    const float* __restrict__ Wv, const float* __restrict__ Wqp,
    const float* __restrict__ Wkp, const float* __restrict__ Wvp,
    const float* __restrict__ bq, const float* __restrict__ bk,
    const float* __restrict__ bv, const float* __restrict__ bqp,
    const float* __restrict__ bkp, const float* __restrict__ bvp,
    const float* __restrict__ Wpb, const float* __restrict__ Wo,
    const float* __restrict__ xs, const float* __restrict__ ln_w,
    const float* __restrict__ ln_b,
    u16* __restrict__ Wth, u16* __restrict__ Wtl,
    float* __restrict__ bcat, float* __restrict__ WpbT,
    u16* __restrict__ WoTh, u16* __restrict__ WoTl,
    u16* __restrict__ snh, u16* __restrict__ snl) {
  __shared__ u16 sh_hi[64][66], sh_lo[64][66];   // stride 66 -> conflict-free
  int blk = blockIdx.x, t = threadIdx.x;
  if (blk < 168) {
    int kb = blk / 28, cb = blk % 28;
    int k0 = kb * 64, c0 = cb * 64;
    for (int e = t; e < 4096; e += 256) {
      int rr = e >> 6, cc = e & 63;
      int k = k0 + rr, c = c0 + cc;
      float v = 0.f;
      if (c < 384)       v = Wq[k*384 + c];
      else if (c < 768)  v = Wk[k*384 + c-384];
      else if (c < 1152) v = Wv[k*384 + c-768];
      else if (c < 1296) v = Wqp[k*144 + c-1152];
      else if (c < 1440) v = Wkp[k*144 + c-1296];
      else if (c < 1728) v = Wvp[k*288 + c-1440];
      u16 h_, l_; split_bf16(v, h_, l_);
      sh_hi[rr][cc] = h_; sh_lo[rr][cc] = l_;
    }
    __syncthreads();
    for (int e = t; e < 4096; e += 256) {
      int cc = e >> 6, kk = e & 63;
      Wth[(size_t)(c0+cc)*DS + k0 + kk] = sh_hi[kk][cc];
      Wtl[(size_t)(c0+cc)*DS + k0 + kk] = sh_lo[kk][cc];
    }
  } else if (blk == 168) {
    for (int e = t; e < NPP + NH*DPAIR; e += 256) {
      if (e < NPP) {
        int c = e;
        float v = 0.f;
        if (c < 384)       v = bq[c];
        else if (c < 768)  v = bk[c-384];
        else if (c < 1152) v = bv[c-768];
        else if (c < 1296) v = bqp[c-1152];
        else if (c < 1440) v = bkp[c-1296];
        else if (c < 1728) v = bvp[c-1440];
        bcat[c] = v;
      } else {
        int e2 = e - NPP;
        int k = e2 / NH, h = e2 % NH;
        WpbT[h*DPAIR + k] = Wpb[e2];
      }
    }
  } else if (blk < 385) {
    int idx = blk - 169;
    int kt = idx % 36, nt = idx / 36;      // Wo is [2304][384]
    int k0 = kt * 64, n0 = nt * 64;
    for (int e = t; e < 4096; e += 256) {
      int rr = e >> 6, cc = e & 63;
      float v = Wo[(size_t)(k0+rr)*384 + n0 + cc];
      u16 h_, l_; split_bf16(v, h_, l_);
      sh_hi[rr][cc] = h_; sh_lo[rr][cc] = l_;
    }
    __syncthreads();
    for (int e = t; e < 4096; e += 256) {
      int cc = e >> 6, kk = e & 63;
      WoTh[(size_t)(n0+cc)*2304 + k0 + kk] = sh_hi[kk][cc];
      WoTl[(size_t)(n0+cc)*2304 + k0 + kk] = sh_lo[kk][cc];
    }
  } else {
    // layernorm row, 256 threads covering 384 elements
    int i = blk - 385;
    float* red = (float*)&sh_hi[0][0];
    float a0 = xs[i*DS + t];
    float a1 = (t < 128) ? xs[i*DS + 256 + t] : 0.f;
    red[t] = a0 + a1; __syncthreads();
    for (int s = 128; s > 0; s >>= 1) { if (t < s) red[t] += red[t+s]; __syncthreads(); }
    float mu = red[0] * (1.f/384.f);
    __syncthreads();
    float d0 = a0 - mu, d1 = (t < 128) ? (a1 - mu) : 0.f;
    red[t] = d0*d0 + d1*d1; __syncthreads();
    for (int s = 128; s > 0; s >>= 1) { if (t < s) red[t] += red[t+s]; __syncthreads(); }
    float rstd = rsqrtf(red[0] * (1.f/384.f) + 1e-5f);
    u16 h_, l_;
    float y0 = d0*rstd*ln_w[t] + ln_b[t];
    split_bf16(y0, h_, l_); snh[i*DS + t] = h_; snl[i*DS + t] = l_;
    if (t < 128) {
      float y1 = d1*rstd*ln_w[256+t] + ln_b[256+t];
      split_bf16(y1, h_, l_); snh[i*DS + 256 + t] = h_; snl[i*DS + 256 + t] = l_;
    }
  }
}

// ---------------------------------------------------------------- MFMA GEMM: C[M][N] = A[M][K] @ Bt[N][K]^T
// 3-term compensated bf16 (AhBh + AhBl + AlBh), f32 accumulate -> ~f32 accuracy.
__global__ __launch_bounds__(256) void k_gemm_mfma(
    const u16* __restrict__ Ah, const u16* __restrict__ Al,
    const u16* __restrict__ Bth, const u16* __restrict__ Btl,
    const float* __restrict__ bias, float* __restrict__ C,
    float* __restrict__ Cpart, int M, int N, int K) {
  int t = threadIdx.x;
  int lane = t & 63, wave = t >> 6;
  int wr = wave >> 1, wc = wave & 1;
  int i0 = blockIdx.y * 64 + wr * 32;
  int j0 = blockIdx.x * 64 + wc * 32;
  int KS = gridDim.z;
  int kper = K / KS;
  size_t kbeg = (size_t)blockIdx.z * kper;
  int lr = lane & 15, lk = (lane >> 4) << 3;

  const u16* a0h = Ah  + (size_t)(i0 + lr) * K + kbeg + lk;
  const u16* a1h = a0h + (size_t)16 * K;
  const u16* a0l = Al  + (size_t)(i0 + lr) * K + kbeg + lk;
  const u16* a1l = a0l + (size_t)16 * K;
  const u16* b0h = Bth + (size_t)(j0 + lr) * K + kbeg + lk;
  const u16* b1h = b0h + (size_t)16 * K;
  const u16* b0l = Btl + (size_t)(j0 + lr) * K + kbeg + lk;
  const u16* b1l = b0l + (size_t)16 * K;

  f32x4 c00 = {0.f,0.f,0.f,0.f}, c01 = c00, c10 = c00, c11 = c00;
  for (int k = 0; k < kper; k += 32) {
    bf16x8 A0h = *(const bf16x8*)(a0h + k);
    bf16x8 A1h = *(const bf16x8*)(a1h + k);
    bf16x8 B0h = *(const bf16x8*)(b0h + k);
    bf16x8 B1h = *(const bf16x8*)(b1h + k);
    bf16x8 A0l = *(const bf16x8*)(a0l + k);
    bf16x8 A1l = *(const bf16x8*)(a1l + k);
    bf16x8 B0l = *(const bf16x8*)(b0l + k);
    bf16x8 B1l = *(const bf16x8*)(b1l + k);
    c00 = __builtin_amdgcn_mfma_f32_16x16x32_bf16(A0h, B0h, c00, 0, 0, 0);
    c01 = __builtin_amdgcn_mfma_f32_16x16x32_bf16(A0h, B1h, c01, 0, 0, 0);
    c10 = __builtin_amdgcn_mfma_f32_16x16x32_bf16(A1h, B0h, c10, 0, 0, 0);
    c11 = __builtin_amdgcn_mfma_f32_16x16x32_bf16(A1h, B1h, c11, 0, 0, 0);
    c00 = __builtin_amdgcn_mfma_f32_16x16x32_bf16(A0h, B0l, c00, 0, 0, 0);
    c01 = __builtin_amdgcn_mfma_f32_16x16x32_bf16(A0h, B1l, c01, 0, 0, 0);
    c10 = __builtin_amdgcn_mfma_f32_16x16x32_bf16(A1h, B0l, c10, 0, 0, 0);
    c11 = __builtin_amdgcn_mfma_f32_16x16x32_bf16(A1h, B1l, c11, 0, 0, 0);
    c00 = __builtin_amdgcn_mfma_f32_16x16x32_bf16(A0l, B0h, c00, 0, 0, 0);
    c01 = __builtin_amdgcn_mfma_f32_16x16x32_bf16(A0l, B1h, c01, 0, 0, 0);
    c10 = __builtin_amdgcn_mfma_f32_16x16x32_bf16(A1l, B0h, c10, 0, 0, 0);
    c11 = __builtin_amdgcn_mfma_f32_16x16x32_bf16(A1l, B1h, c11, 0, 0, 0);
  }

  int orow = (lane >> 4) << 2;
  int col0 = j0 + lr, col1 = j0 + 16 + lr;
  if (KS == 1) {
    float bb0 = bias[col0], bb1 = bias[col1];
    #pragma unroll
    for (int r = 0; r < 4; r++) {
      int row0 = i0 + orow + r, row1 = row0 + 16;
      C[(size_t)row0*N + col0] = c00[r] + bb0;
      C[(size_t)row0*N + col1] = c01[r] + bb1;
      C[(size_t)row1*N + col0] = c10[r] + bb0;
      C[(size_t)row1*N + col1] = c11[r] + bb1;
    }
  } else {
    float* dst = Cpart + (size_t)blockIdx.z * M * N;
    #pragma unroll
    for (int r = 0; r < 4; r++) {
      int row0 = i0 + orow + r, row1 = row0 + 16;
      dst[(size_t)row0*N + col0] = c00[r];
      dst[(size_t)row0*N + col1] = c01[r];
      dst[(size_t)row1*N + col0] = c10[r];
      dst[(size_t)row1*N + col1] = c11[r];
    }
  }
}

__global__ void k_reduce_bias(const float* __restrict__ part, const float* __restrict__ bias,
                              float* __restrict__ out, int MN, int N, int KS) {
  int e = blockIdx.x * 256 + threadIdx.x;
  if (e >= MN) return;
  float s = bias[e % N];
  for (int z = 0; z < KS; z++) s += part[(size_t)z*MN + e];
  out[e] = s;
}

// ---------------------------------------------------------------- fused feature-build + logits MFMA
__global__ __launch_bounds__(256) void k_feat_logits(
    const float* __restrict__ C1, const float* __restrict__ rot,
    const float* __restrict__ trans, const float* __restrict__ gamma,
    const float* __restrict__ w_c, const float* __restrict__ w_l,
    float* __restrict__ S) {
  __shared__ u16 Ash[64][72], Asl[64][72], Bsh[64][72], Bsl[64][72];  // 36.9 KB
  int h = blockIdx.z;
  int i0 = blockIdx.y * 64, j0 = blockIdx.x * 64;
  int t = threadIdx.x;

  if (t < 128) {
    int row = t & 63, side = t >> 6;      // side 0 = A (query), 1 = B (key)
    int gi = (side ? j0 : i0) + row;
    float R[9], tr[3];
    #pragma unroll
    for (int r = 0; r < 9; r++) R[r] = rot[(size_t)gi*9 + r];
    #pragma unroll
    for (int r = 0; r < 3; r++) tr[r] = trans[(size_t)gi*3 + r];
    float sc = w_c[0] * rsqrtf(32.f);
    float gp = gamma[h] * w_l[0];
    u16 (*Fh)[72] = side ? Bsh : Ash;
    u16 (*Fl)[72] = side ? Bsl : Asl;
    const float* qk = C1 + (size_t)gi*NPP + (side ? 384 : 0) + h*32;
    u16 h_, l_;
    #pragma unroll 8
    for (int d = 0; d < 32; d++) {
      float v = side ? qk[d] : sc*qk[d];
      split_bf16(v, h_, l_); Fh[row][d] = h_; Fl[row][d] = l_;
    }
    const float* pp = C1 + (size_t)gi*NPP + (side ? 1296 : 1152) + h*12;
    float ss = 0.f;
    #pragma unroll
    for (int p = 0; p < 4; p++) {
      float x = pp[p*3], y = pp[p*3+1], z = pp[p*3+2];
      #pragma unroll
      for (int r = 0; r < 3; r++) {
        float g = fmaf(R[r*3],x, fmaf(R[r*3+1],y, fmaf(R[r*3+2],z, tr[r])));
        float v = side ? g : gp*g;
        split_bf16(v, h_, l_); Fh[row][32+p*3+r] = h_; Fl[row][32+p*3+r] = l_;
        ss = fmaf(g,g,ss);
      }
    }
    float c44 = side ? 1.f : -0.5f*gp*ss;
    float c45 = side ? -0.5f*gp*ss : 1.f;
    split_bf16(c44, h_, l_); Fh[row][44] = h_; Fl[row][44] = l_;
    split_bf16(c45, h_, l_); Fh[row][45] = h_; Fl[row][45] = l_;
    #pragma unroll
    for (int d = 46; d < 64; d++) { Fh[row][d] = 0; Fl[row][d] = 0; }
  }
  __syncthreads();

  int lane = t & 63, wave = t >> 6, wr = wave >> 1, wc = wave & 1;
  int lr = lane & 15, lk = (lane >> 4) << 3;
  f32x4 c00 = {0.f,0.f,0.f,0.f}, c01 = c00, c10 = c00, c11 = c00;
  #pragma unroll
  for (int ks = 0; ks < 64; ks += 32) {
    bf16x8 A0h = *(const bf16x8*)&Ash[wr*32 + lr][ks + lk];
    bf16x8 A1h = *(const bf16x8*)&Ash[wr*32 + 16 + lr][ks + lk];
    bf16x8 B0h = *(const bf16x8*)&Bsh[wc*32 + lr][ks + lk];
    bf16x8 B1h = *(const bf16x8*)&Bsh[wc*32 + 16 + lr][ks + lk];
    bf16x8 A0l = *(const bf16x8*)&Asl[wr*32 + lr][ks + lk];
    bf16x8 A1l = *(const bf16x8*)&Asl[wr*32 + 16 + lr][ks + lk];
    bf16x8 B0l = *(const bf16x8*)&Bsl[wc*32 + lr][ks + lk];
    bf16x8 B1l = *(const bf16x8*)&Bsl[wc*32 + 16 + lr][ks + lk];
    c00 = __builtin_amdgcn_mfma_f32_16x16x32_bf16(A0h, B0h, c00, 0, 0, 0);
    c01 = __builtin_amdgcn_mfma_f32_16x16x32_bf16(A0h, B1h, c01, 0, 0, 0);
    c10 = __builtin_amdgcn_mfma_f32_16x16x32_bf16(A1h, B0h, c10, 0, 0, 0);
    c11 = __builtin_amdgcn_mfma_f32_16x16x32_bf16(A1h, B1h, c11, 0, 0, 0);
    c00 = __builtin_amdgcn_mfma_f32_16x16x32_bf16(A0h, B0l, c00, 0, 0, 0);
    c01 = __builtin_amdgcn_mfma_f32_16x16x32_bf16(A0h, B1l, c01, 0, 0, 0);
    c10 = __builtin_amdgcn_mfma_f32_16x16x32_bf16(A1h, B0l, c10, 0, 0, 0);
    c11 = __builtin_amdgcn_mfma_f32_16x16x32_bf16(A1h, B1l, c11, 0, 0, 0);
    c00 = __builtin_amdgcn_mfma_f32_16x16x32_bf16(A0l, B0h, c00, 0, 0, 0);
    c01 = __builtin_amdgcn_mfma_f32_16x16x32_bf16(A0l, B1h, c01, 0, 0, 0);
    c10 = __builtin_amdgcn_mfma_f32_16x16x32_bf16(A1l, B0h, c10, 0, 0, 0);
    c11 = __builtin_amdgcn_mfma_f32_16x16x32_bf16(A1l, B1h, c11, 0, 0, 0);
  }

  int orow = (lane >> 4) << 2;
  int col0 = j0 + wc*32 + lr, col1 = col0 + 16;
  int rbase = i0 + wr*32 + orow;
  #pragma unroll
  for (int r = 0; r < 4; r++) {
    S[((size_t)h*LQ + rbase + r)*LQ + col0]      = c00[r];
    S[((size_t)h*LQ + rbase + r)*LQ + col1]      = c01[r];
    S[((size_t)h*LQ + rbase + 16 + r)*LQ + col0] = c10[r];
    S[((size_t)h*LQ + rbase + 16 + r)*LQ + col1] = c11[r];
  }
}

// ---------------------------------------------------------------- per-i pair stage (resident, prefetched):
// one block per i. Loops all 8 j-chunks: [reg-prefetch next tile] -> pair-bias
// GEMV + chunk softmax (writes S = e^{l-m_c}) -> online-rescaled pair_out
// accumulation in registers. Epilogue: denominators, scs_g write, cross-strip
// reduce, comb cols 768..2304 (split-bf16).
__global__ __launch_bounds__(256) void k_pair(
    const float* __restrict__ pair, const float* __restrict__ WpbT,
    const float* __restrict__ bpb, const float* __restrict__ mask,
    float* S, float* __restrict__ scs_g,
    u16* __restrict__ combh, u16* __restrict__ combl) {
  __shared__ float tile[TJC*133];        // 34.0 KB
  __shared__ float wt[NH*TJC];           // 3 KB
  __shared__ float msc[NC][NH], ssc[NC][NH];
  __shared__ float rfac[NH], dinv[NH];
  int i = blockIdx.x, t = threadIdx.x;
  int j = t & 63;
  int hg = t >> 6;                       // wave 0..3 owns heads 3hg..3hg+2
  int h0 = hg * 3;
  int dg = t & 31, strip = t >> 5, jb = strip*8;

  float b0 = bpb[h0], b1 = bpb[h0+1], b2 = bpb[h0+2];
  float mi = mask[i];
  const float* w0p = WpbT + (size_t)(h0+0)*DPAIR;
  const float* w1p = WpbT + (size_t)(h0+1)*DPAIR;
  const float* w2p = WpbT + (size_t)(h0+2)*DPAIR;

  float4 acc[NH];
  #pragma unroll
  for (int h = 0; h < NH; h++) acc[h] = make_float4(0.f,0.f,0.f,0.f);
  float mrun[3] = {-3.0e38f, -3.0e38f, -3.0e38f};

  // preload + stage chunk 0
  float4 pf[8];
  {
    const float4* src = (const float4*)(pair + (size_t)i*LQ*DPAIR);
    #pragma unroll
    for (int u = 0; u < 8; u++) pf[u] = src[t + u*256];
  }
  #pragma unroll
  for (int u = 0; u < 8; u++) {
    int e = t + u*256; int row = e >> 5, c4 = e & 31;
    *(float4*)&tile[row*133 + c4*4] = pf[u];
  }
  __syncthreads();

  for (int c = 0; c < NC; c++) {
    // prefetch next chunk into registers (hides HBM under phases A+C)
    if (c < NC-1) {
      const float4* src = (const float4*)(pair + ((size_t)i*LQ + (c+1)*TJC)*DPAIR);
      #pragma unroll
      for (int u = 0; u < 8; u++) pf[u] = src[t + u*256];
    }
    int j0 = c*TJC;
    // phase A: logits = S + bias + pair-bias GEMV from LDS tile
    float l0 = S[((size_t)(h0+0)*LQ + i)*LQ + j0 + j] + b0;
    float l1 = S[((size_t)(h0+1)*LQ + i)*LQ + j0 + j] + b1;
    float l2 = S[((size_t)(h0+2)*LQ + i)*LQ + j0 + j] + b2;
    {
      float a0 = 0.f, a1 = 0.f, a2 = 0.f;
      #pragma unroll 8
      for (int k = 0; k < DPAIR; k += 4) {
        float4 pv = *(const float4*)&tile[j*133 + k];
        float4 w0 = *(const float4*)(w0p + k);
        float4 w1 = *(const float4*)(w1p + k);
        float4 w2 = *(const float4*)(w2p + k);
        a0 = fmaf(pv.x,w0.x, fmaf(pv.y,w0.y, fmaf(pv.z,w0.z, fmaf(pv.w,w0.w, a0))));
        a1 = fmaf(pv.x,w1.x, fmaf(pv.y,w1.y, fmaf(pv.z,w1.z, fmaf(pv.w,w1.w, a1))));
        a2 = fmaf(pv.x,w2.x, fmaf(pv.y,w2.y, fmaf(pv.z,w2.z, fmaf(pv.w,w2.w, a2))));
      }
      l0 += a0; l1 += a1; l2 += a2;
      bool dead = (mi * mask[j0 + j] <= 0.f);
      if (dead) { l0 = -1e9f; l1 = -1e9f; l2 = -1e9f; }
    }
    // chunk softmax + wave-local running-max update
    #pragma unroll
    for (int q = 0; q < 3; q++) {
      float lv = (q==0) ? l0 : (q==1) ? l1 : l2;
      float m = lv;
      #pragma unroll
      for (int o = 32; o > 0; o >>= 1) m = fmaxf(m, __shfl_xor(m, o, 64));
      float w = __expf(lv - m);
      float sm = w;
      #pragma unroll
      for (int o = 32; o > 0; o >>= 1) sm += __shfl_xor(sm, o, 64);
      float mnew = fmaxf(mrun[q], m);
      float f  = __expf(m - mnew);        // lane-uniform
      float rf = __expf(mrun[q] - mnew);  // lane-uniform
      mrun[q] = mnew;
      wt[(h0+q)*TJC + j] = w * f;
      S[((size_t)(h0+q)*LQ + i)*LQ + j0 + j] = w;
      if (j == 0) { msc[c][h0+q] = m; ssc[c][h0+q] = sm; rfac[h0+q] = rf; }
    }
    __syncthreads();   // wt + rfac ready
    // phase C: online-rescaled accumulation
    {
      float4 pv[8];
      #pragma unroll
      for (int q = 0; q < 8; q++) pv[q] = *(const float4*)&tile[(jb+q)*133 + dg*4];
      #pragma unroll
      for (int h = 0; h < NH; h++) {
        float rf = rfac[h];
        float4 w0 = *(const float4*)&wt[h*TJC + jb];
        float4 w1 = *(const float4*)&wt[h*TJC + jb + 4];
        float wq[8] = {w0.x,w0.y,w0.z,w0.w,w1.x,w1.y,w1.z,w1.w};
        float4 a = acc[h];
        a.x *= rf; a.y *= rf; a.z *= rf; a.w *= rf;
        #pragma unroll
        for (int q = 0; q < 8; q++) {
          a.x = fmaf(wq[q], pv[q].x, a.x);
          a.y = fmaf(wq[q], pv[q].y, a.y);
          a.z = fmaf(wq[q], pv[q].z, a.z);
          a.w = fmaf(wq[q], pv[q].w, a.w);
        }
        acc[h] = a;
      }
    }
    __syncthreads();   // tile reads done
    if (c < NC-1) {
      #pragma unroll
      for (int u = 0; u < 8; u++) {
        int e = t + u*256; int row = e >> 5, c4 = e & 31;
        *(float4*)&tile[row*133 + c4*4] = pf[u];
      }
      __syncthreads(); // tile ready for next phase A
    }
  }

  // denominators + scs_g (softmax wave lane 0 owns its 3 heads)
  if (j == 0) {
    #pragma unroll
    for (int q = 0; q < 3; q++) {
      float M = mrun[q];
      float den = 0.f;
      #pragma unroll
      for (int c = 0; c < NC; c++) den += ssc[c][h0+q] * __expf(msc[c][h0+q] - M);
      float inv = 1.f / den;
      dinv[h0+q] = inv;
      #pragma unroll
      for (int c = 0; c < NC; c++)
        scs_g[((size_t)i*NH + h0+q)*NC + c] = __expf(msc[c][h0+q] - M) * inv;
    }
  }

  // cross-strip reduction (two halves of 4 strips), then comb write
  float4* red4 = (float4*)tile;    // 4*12*32 = 1536 float4 <= 2128 cap
  float4 tot[2];
  tot[0] = make_float4(0.f,0.f,0.f,0.f);
  tot[1] = make_float4(0.f,0.f,0.f,0.f);
  #pragma unroll
  for (int half = 0; half < 2; half++) {
    if ((strip >> 2) == half) {
      #pragma unroll
      for (int h = 0; h < NH; h++)
        red4[(((strip & 3)*NH) + h)*32 + dg] = acc[h];
    }
    __syncthreads();
    for (int e = t, u = 0; e < NH*32; e += 256, u++) {
      int rh = e >> 5, rd = e & 31;
      #pragma unroll
      for (int s4 = 0; s4 < 4; s4++) {
        float4 v = red4[((s4*NH) + rh)*32 + rd];
        tot[u].x += v.x; tot[u].y += v.y; tot[u].z += v.z; tot[u].w += v.w;
      }
    }
    __syncthreads();
  }
  for (int e = t, u = 0; e < NH*32; e += 256, u++) {
    int rh = e >> 5, rd = e & 31;
    float inv = dinv[rh];
    size_t dst = (size_t)i*2304 + 768 + rh*DPAIR + rd*4;
    u16 h_, l_;
    split_bf16(tot[u].x * inv, h_, l_); combh[dst+0] = h_; combl[dst+0] = l_;
    split_bf16(tot[u].y * inv, h_, l_); combh[dst+1] = h_; combl[dst+1] = l_;
    split_bf16(tot[u].z * inv, h_, l_); combh[dst+2] = h_; combl[dst+2] = l_;
    split_bf16(tot[u].w * inv, h_, l_); combh[dst+3] = h_; combl[dst+3] = l_;
  }
}

// ---------------------------------------------------------------- fused attention tail:
// per block (64-row i-tile, head h): scs from scs_g; K-loop j-chunks staging
// normalized weights + V/vg operand in LDS; compensated MFMA; avpts epilogue.
__global__ __launch_bounds__(256, 2) void k_attn_full(
    const float* __restrict__ S, const float* __restrict__ scs_g,
    const float* __restrict__ C1, const float* __restrict__ rot,
    const float* __restrict__ trans,
    u16* __restrict__ combh, u16* __restrict__ combl) {
  __shared__ u16 Ash[64][72], Asl[64][72], Vsh[64][72], Vsl[64][72];  // 36.9 KB
  __shared__ float scs_l[64][NC];                                     // 2 KB
  __shared__ float Of[64][66];                                        // 16.9 KB
  int i0 = blockIdx.x * 64;
  int h = blockIdx.y;
  int t = threadIdx.x, lane = t & 63, wave = t >> 6, wr = wave >> 1, wc = wave & 1;
  int lr = lane & 15, lk = (lane >> 4) << 3;

  if (t < 64) {
    #pragma unroll
    for (int c = 0; c < NC; c++)
      scs_l[t][c] = scs_g[((size_t)(i0+t)*NH + h)*NC + c];
  }
  __syncthreads();

  f32x4 c00 = {0.f,0.f,0.f,0.f}, c01 = c00, c10 = c00, c11 = c00;
  for (int jc = 0; jc < 8; jc++) {
    int j0 = jc * 64;
    // stage normalized attention weights A[m][j]
    for (int e = t; e < 4096; e += 256) {
      int m = e >> 6, j = e & 63;
      float w = S[((size_t)h*LQ + i0 + m)*LQ + j0 + j] * scs_l[m][jc];
      u16 h_, l_; split_bf16(w, h_, l_);
      Ash[m][j] = h_; Asl[m][j] = l_;
    }
    // stage V^T[n][j]: n<32 = v, 32..55 = rotated vg, 56..63 = 0
    {
      int j = t & 63, ng = t >> 6;
      int gj = j0 + j;
      u16 h_, l_;
      if (ng < 2) {
        const float* vrow = C1 + (size_t)gj*NPP + 768 + h*32 + ng*16;
        #pragma unroll
        for (int q = 0; q < 16; q++) {
          split_bf16(vrow[q], h_, l_);
          Vsh[ng*16 + q][j] = h_; Vsl[ng*16 + q][j] = l_;
        }
      } else {
        const float* prow = C1 + (size_t)gj*NPP + 1440 + h*24;
        const float* R = rot + (size_t)gj*9;
        const float* tr = trans + (size_t)gj*3;
        int nbase = ng * 16;   // 32 or 48
        #pragma unroll
        for (int q = 0; q < 16; q++) {
          int n = nbase + q;
          float val = 0.f;
          if (n < 56) {
            int pp = (n - 32) / 3, rr = (n - 32) % 3;
            float x = prow[pp*3], y = prow[pp*3+1], z = prow[pp*3+2];
            val = fmaf(R[rr*3], x, fmaf(R[rr*3+1], y, fmaf(R[rr*3+2], z, tr[rr])));
          }
          split_bf16(val, h_, l_);
          Vsh[n][j] = h_; Vsl[n][j] = l_;
        }
      }
    }
    __syncthreads();
    #pragma unroll
    for (int ks = 0; ks < 64; ks += 32) {
      bf16x8 A0h = *(const bf16x8*)&Ash[wr*32 + lr][ks + lk];
      bf16x8 A1h = *(const bf16x8*)&Ash[wr*32 + 16 + lr][ks + lk];
      bf16x8 B0h = *(const bf16x8*)&Vsh[wc*32 + lr][ks + lk];
      bf16x8 B1h = *(const bf16x8*)&Vsh[wc*32 + 16 + lr][ks + lk];
      bf16x8 A0l = *(const bf16x8*)&Asl[wr*32 + lr][ks + lk];
      bf16x8 A1l = *(const bf16x8*)&Asl[wr*32 + 16 + lr][ks + lk];
      bf16x8 B0l = *(const bf16x8*)&Vsl[wc*32 + lr][ks + lk];
      bf16x8 B1l = *(const bf16x8*)&Vsl[wc*32 + 16 + lr][ks + lk];
      c00 = __builtin_amdgcn_mfma_f32_16x16x32_bf16(A0h, B0h, c00, 0, 0, 0);
      c01 = __builtin_amdgcn_mfma_f32_16x16x32_bf16(A0h, B1h, c01, 0, 0, 0);
      c10 = __builtin_amdgcn_mfma_f32_16x16x32_bf16(A1h, B0h, c10, 0, 0, 0);
      c11 = __builtin_amdgcn_mfma_f32_16x16x32_bf16(A1h, B1h, c11, 0, 0, 0);
      c00 = __builtin_amdgcn_mfma_f32_16x16x32_bf16(A0h, B0l, c00, 0, 0, 0);
      c01 = __builtin_amdgcn_mfma_f32_16x16x32_bf16(A0h, B1l, c01, 0, 0, 0);
      c10 = __builtin_amdgcn_mfma_f32_16x16x32_bf16(A1h, B0l, c10, 0, 0, 0);
      c11 = __builtin_amdgcn_mfma_f32_16x16x32_bf16(A1h, B1l, c11, 0, 0, 0);
      c00 = __builtin_amdgcn_mfma_f32_16x16x32_bf16(A0l, B0h, c00, 0, 0, 0);
      c01 = __builtin_amdgcn_mfma_f32_16x16x32_bf16(A0l, B1h, c01, 0, 0, 0);
      c10 = __builtin_amdgcn_mfma_f32_16x16x32_bf16(A1l, B0h, c10, 0, 0, 0);
      c11 = __builtin_amdgcn_mfma_f32_16x16x32_bf16(A1l, B1h, c11, 0, 0, 0);
    }
    __syncthreads();
  }

  // gather output tile in LDS
  int orow = (lane >> 4) << 2;
  #pragma unroll
  for (int r = 0; r < 4; r++) {
    Of[wr*32 + orow + r][wc*32 + lr]           = c00[r];
    Of[wr*32 + orow + r][wc*32 + 16 + lr]      = c01[r];
    Of[wr*32 + 16 + orow + r][wc*32 + lr]      = c10[r];
    Of[wr*32 + 16 + orow + r][wc*32 + 16 + lr] = c11[r];
  }
  __syncthreads();

  // avpts epilogue: seq part + point transform
  for (int e = t; e < 64*40; e += 256) {
    int w = e % 40, m = e / 40;
    int gi = i0 + m;
    u16 h_, l_;
    if (w < 32) {
      split_bf16(Of[m][w], h_, l_);
      combh[(size_t)gi*2304 + h*32 + w] = h_;
      combl[(size_t)gi*2304 + h*32 + w] = l_;
    } else {
      int pp = w - 32;
      float g0 = Of[m][32+pp*3], g1 = Of[m][32+pp*3+1], g2 = Of[m][32+pp*3+2];
      const float* R = rot + (size_t)gi*9;
      const float* tr = trans + (size_t)gi*3;
      float x = g0 - tr[0], y = g1 - tr[1], z = g2 - tr[2];
      float lx = fmaf(R[0],x, fmaf(R[3],y, R[6]*z));
      float ly = fmaf(R[1],x, fmaf(R[4],y, R[7]*z));
      float lz = fmaf(R[2],x, fmaf(R[5],y, R[8]*z));
      float nrm = sqrtf(fmaf(lx,lx, fmaf(ly,ly, lz*lz)));
      size_t dst = (size_t)gi*2304 + 384 + ((size_t)h*8 + pp)*4;
      split_bf16(nrm, h_, l_); combh[dst+0] = h_; combl[dst+0] = l_;
      split_bf16(lx,  h_, l_); combh[dst+1] = h_; combl[dst+1] = l_;
      split_bf16(ly,  h_, l_); combh[dst+2] = h_; combl[dst+2] = l_;
      split_bf16(lz,  h_, l_); combh[dst+3] = h_; combl[dst+3] = l_;
    }
  }
}

// ================================================================ launcher
extern "C" void kernel_launch(void* const* d_in, const int* in_sizes, int n_in,
                              void* d_out, int out_size, void* d_ws, size_t ws_size,
                              hipStream_t stream) {
  const float* single = (const float*)d_in[0];
  const float* pair   = (const float*)d_in[1];
  const float* rot    = (const float*)d_in[2];
  const float* trans  = (const float*)d_in[3];
  const float* mask   = (const float*)d_in[4];
  const float* ln_w   = (const float*)d_in[5];
  const float* ln_b   = (const float*)d_in[6];
  const float* Wq     = (const float*)d_in[7];
  const float* bq     = (const float*)d_in[8];
  const float* Wk     = (const float*)d_in[9];
  const float* bk     = (const float*)d_in[10];
  const float* Wv     = (const float*)d_in[11];
  const float* bv     = (const float*)d_in[12];
  const float* Wqp    = (const float*)d_in[13];
  const float* bqp    = (const float*)d_in[14];
  const float* Wkp    = (const float*)d_in[15];
  const float* bkp    = (const float*)d_in[16];
  const float* Wvp    = (const float*)d_in[17];
  const float* bvp    = (const float*)d_in[18];
  const float* Wpb    = (const float*)d_in[19];
  const float* bpb    = (const float*)d_in[20];
  const float* Wo     = (const float*)d_in[21];
  const float* bo     = (const float*)d_in[22];
  const float* w_c    = (const float*)d_in[23];
  const float* w_l    = (const float*)d_in[24];
  const float* gamma  = (const float*)d_in[25];
  float* out = (float*)d_out;

  float* p = (float*)d_ws;
  auto alloc = [&](size_t n) { float* r = p; p += n; return r; };
  u16* WcatTh = (u16*)alloc((size_t)NPP*DS/2);
  u16* WcatTl = (u16*)alloc((size_t)NPP*DS/2);
  u16* snh    = (u16*)alloc((size_t)LQ*DS/2);
  u16* snl    = (u16*)alloc((size_t)LQ*DS/2);
  u16* WoTh   = (u16*)alloc((size_t)DS*2304/2);
  u16* WoTl   = (u16*)alloc((size_t)DS*2304/2);
  u16* combh  = (u16*)alloc((size_t)LQ*2304/2);
  u16* combl  = (u16*)alloc((size_t)LQ*2304/2);
  float* bcat    = alloc(NPP);
  float* WpbT    = alloc((size_t)NH*DPAIR);
  float* C1      = alloc((size_t)LQ*NPP);
  float* S       = alloc((size_t)NH*LQ*LQ);
  float* scs_g   = alloc((size_t)LQ*NH*NC);
  float* outpart = alloc((size_t)8*LQ*DS);

  k_prep<<<dim3(897), 256, 0, stream>>>(
      Wq, Wk, Wv, Wqp, Wkp, Wvp, bq, bk, bv, bqp, bkp, bvp, Wpb, Wo,
      single, ln_w, ln_b, WcatTh, WcatTl, bcat, WpbT, WoTh, WoTl, snh, snl);
  k_gemm_mfma<<<dim3(NPP/64, LQ/64, 1), 256, 0, stream>>>(
      snh, snl, WcatTh, WcatTl, bcat, C1, nullptr, LQ, NPP, DS);
  k_feat_logits<<<dim3(LQ/64, LQ/64, NH), 256, 0, stream>>>(
      C1, rot, trans, gamma, w_c, w_l, S);
  k_pair<<<dim3(LQ), 256, 0, stream>>>(
      pair, WpbT, bpb, mask, S, scs_g, combh, combl);
  k_attn_full<<<dim3(LQ/64, NH), 256, 0, stream>>>(
      S, scs_g, C1, rot, trans, combh, combl);
  k_gemm_mfma<<<dim3(DS/64, LQ/64, 8), 256, 0, stream>>>(
      combh, combl, WoTh, WoTl, nullptr, nullptr, outpart, LQ, DS, 2304);
  k_reduce_bias<<<dim3((LQ*DS + 255)/256), 256, 0, stream>>>(outpart, bo, out, LQ*DS, DS, 8);
}

// Round 6
// 376.093 us; speedup vs baseline: 1.1194x; 1.1194x over previous
//
#include <hip/hip_runtime.h>
#include <math.h>

// Problem constants
#define LQ    512
#define DS    384
#define DPAIR 128
#define NH    12
#define NPP   1792   // padded projection width
#define TJC   64     // j-chunk for pair kernel
#define NC    8      // number of j-chunks (LQ/TJC)

typedef unsigned short u16;
typedef unsigned int   u32;
typedef __attribute__((ext_vector_type(8))) short bf16x8;  // 8 bf16 in 4 VGPRs
typedef __attribute__((ext_vector_type(4))) float f32x4;

// round-to-nearest-even f32 -> bf16 bits
__device__ inline u16 bf16_rne(float x) {
  u32 u = __float_as_uint(x);
  u32 r = (u + 0x7FFFu + ((u >> 16) & 1u)) >> 16;
  return (u16)r;
}
// split x ~= hi + lo (both bf16); residual ~2^-17 relative
__device__ inline void split_bf16(float x, u16& h, u16& l) {
  u16 hb = bf16_rne(x);
  float hf = __uint_as_float(((u32)hb) << 16);
  h = hb;
  l = bf16_rne(x - hf);
}

// async 16B global->LDS (dest = wave-uniform base + lane*16)
__device__ inline void async_copy16(const float* g, float* l) {
  auto gp = (const __attribute__((address_space(1))) float*)(g);
  auto lp = (__attribute__((address_space(3))) float*)(l);
  __builtin_amdgcn_global_load_lds(gp, lp, 16, 0, 0);
}

// ---------------------------------------------------------------- fused prep:
// blocks 0..167   : Wcat transpose+split tiles -> WcatT [NPP][DS] bf16 hi/lo
// block  168      : bcat + WpbT
// blocks 169..384 : Wo transpose+split tiles   -> WoT [384][2304] bf16 hi/lo
// blocks 385..896 : layernorm rows -> sn split-bf16
__global__ __launch_bounds__(256) void k_prep(
    const float* __restrict__ Wq, const float* __restrict__ Wk,
    const float* __restrict__ Wv, const float* __restrict__ Wqp,
    const float* __restrict__ Wkp, const float* __restrict__ Wvp,
    const float* __restrict__ bq, const float* __restrict__ bk,
    const float* __restrict__ bv, const float* __restrict__ bqp,
    const float* __restrict__ bkp, const float* __restrict__ bvp,
    const float* __restrict__ Wpb, const float* __restrict__ Wo,
    const float* __restrict__ xs, const float* __restrict__ ln_w,
    const float* __restrict__ ln_b,
    u16* __restrict__ Wth, u16* __restrict__ Wtl,
    float* __restrict__ bcat, float* __restrict__ WpbT,
    u16* __restrict__ WoTh, u16* __restrict__ WoTl,
    u16* __restrict__ snh, u16* __restrict__ snl) {
  __shared__ u16 sh_hi[64][66], sh_lo[64][66];   // stride 66 -> conflict-free
  int blk = blockIdx.x, t = threadIdx.x;
  if (blk < 168) {
    int kb = blk / 28, cb = blk % 28;
    int k0 = kb * 64, c0 = cb * 64;
    for (int e = t; e < 4096; e += 256) {
      int rr = e >> 6, cc = e & 63;
      int k = k0 + rr, c = c0 + cc;
      float v = 0.f;
      if (c < 384)       v = Wq[k*384 + c];
      else if (c < 768)  v = Wk[k*384 + c-384];
      else if (c < 1152) v = Wv[k*384 + c-768];
      else if (c < 1296) v = Wqp[k*144 + c-1152];
      else if (c < 1440) v = Wkp[k*144 + c-1296];
      else if (c < 1728) v = Wvp[k*288 + c-1440];
      u16 h_, l_; split_bf16(v, h_, l_);
      sh_hi[rr][cc] = h_; sh_lo[rr][cc] = l_;
    }
    __syncthreads();
    for (int e = t; e < 4096; e += 256) {
      int cc = e >> 6, kk = e & 63;
      Wth[(size_t)(c0+cc)*DS + k0 + kk] = sh_hi[kk][cc];
      Wtl[(size_t)(c0+cc)*DS + k0 + kk] = sh_lo[kk][cc];
    }
  } else if (blk == 168) {
    for (int e = t; e < NPP + NH*DPAIR; e += 256) {
      if (e < NPP) {
        int c = e;
        float v = 0.f;
        if (c < 384)       v = bq[c];
        else if (c < 768)  v = bk[c-384];
        else if (c < 1152) v = bv[c-768];
        else if (c < 1296) v = bqp[c-1152];
        else if (c < 1440) v = bkp[c-1296];
        else if (c < 1728) v = bvp[c-1440];
        bcat[c] = v;
      } else {
        int e2 = e - NPP;
        int k = e2 / NH, h = e2 % NH;
        WpbT[h*DPAIR + k] = Wpb[e2];
      }
    }
  } else if (blk < 385) {
    int idx = blk - 169;
    int kt = idx % 36, nt = idx / 36;      // Wo is [2304][384]
    int k0 = kt * 64, n0 = nt * 64;
    for (int e = t; e < 4096; e += 256) {
      int rr = e >> 6, cc = e & 63;
      float v = Wo[(size_t)(k0+rr)*384 + n0 + cc];
      u16 h_, l_; split_bf16(v, h_, l_);
      sh_hi[rr][cc] = h_; sh_lo[rr][cc] = l_;
    }
    __syncthreads();
    for (int e = t; e < 4096; e += 256) {
      int cc = e >> 6, kk = e & 63;
      WoTh[(size_t)(n0+cc)*2304 + k0 + kk] = sh_hi[kk][cc];
      WoTl[(size_t)(n0+cc)*2304 + k0 + kk] = sh_lo[kk][cc];
    }
  } else {
    // layernorm row, 256 threads covering 384 elements
    int i = blk - 385;
    float* red = (float*)&sh_hi[0][0];
    float a0 = xs[i*DS + t];
    float a1 = (t < 128) ? xs[i*DS + 256 + t] : 0.f;
    red[t] = a0 + a1; __syncthreads();
    for (int s = 128; s > 0; s >>= 1) { if (t < s) red[t] += red[t+s]; __syncthreads(); }
    float mu = red[0] * (1.f/384.f);
    __syncthreads();
    float d0 = a0 - mu, d1 = (t < 128) ? (a1 - mu) : 0.f;
    red[t] = d0*d0 + d1*d1; __syncthreads();
    for (int s = 128; s > 0; s >>= 1) { if (t < s) red[t] += red[t+s]; __syncthreads(); }
    float rstd = rsqrtf(red[0] * (1.f/384.f) + 1e-5f);
    u16 h_, l_;
    float y0 = d0*rstd*ln_w[t] + ln_b[t];
    split_bf16(y0, h_, l_); snh[i*DS + t] = h_; snl[i*DS + t] = l_;
    if (t < 128) {
      float y1 = d1*rstd*ln_w[256+t] + ln_b[256+t];
      split_bf16(y1, h_, l_); snh[i*DS + 256 + t] = h_; snl[i*DS + 256 + t] = l_;
    }
  }
}

// ---------------------------------------------------------------- MFMA GEMM: C[M][N] = A[M][K] @ Bt[N][K]^T
// 3-term compensated bf16 (AhBh + AhBl + AlBh), f32 accumulate -> ~f32 accuracy.
__global__ __launch_bounds__(256) void k_gemm_mfma(
    const u16* __restrict__ Ah, const u16* __restrict__ Al,
    const u16* __restrict__ Bth, const u16* __restrict__ Btl,
    const float* __restrict__ bias, float* __restrict__ C,
    float* __restrict__ Cpart, int M, int N, int K) {
  int t = threadIdx.x;
  int lane = t & 63, wave = t >> 6;
  int wr = wave >> 1, wc = wave & 1;
  int i0 = blockIdx.y * 64 + wr * 32;
  int j0 = blockIdx.x * 64 + wc * 32;
  int KS = gridDim.z;
  int kper = K / KS;
  size_t kbeg = (size_t)blockIdx.z * kper;
  int lr = lane & 15, lk = (lane >> 4) << 3;

  const u16* a0h = Ah  + (size_t)(i0 + lr) * K + kbeg + lk;
  const u16* a1h = a0h + (size_t)16 * K;
  const u16* a0l = Al  + (size_t)(i0 + lr) * K + kbeg + lk;
  const u16* a1l = a0l + (size_t)16 * K;
  const u16* b0h = Bth + (size_t)(j0 + lr) * K + kbeg + lk;
  const u16* b1h = b0h + (size_t)16 * K;
  const u16* b0l = Btl + (size_t)(j0 + lr) * K + kbeg + lk;
  const u16* b1l = b0l + (size_t)16 * K;

  f32x4 c00 = {0.f,0.f,0.f,0.f}, c01 = c00, c10 = c00, c11 = c00;
  for (int k = 0; k < kper; k += 32) {
    bf16x8 A0h = *(const bf16x8*)(a0h + k);
    bf16x8 A1h = *(const bf16x8*)(a1h + k);
    bf16x8 B0h = *(const bf16x8*)(b0h + k);
    bf16x8 B1h = *(const bf16x8*)(b1h + k);
    bf16x8 A0l = *(const bf16x8*)(a0l + k);
    bf16x8 A1l = *(const bf16x8*)(a1l + k);
    bf16x8 B0l = *(const bf16x8*)(b0l + k);
    bf16x8 B1l = *(const bf16x8*)(b1l + k);
    c00 = __builtin_amdgcn_mfma_f32_16x16x32_bf16(A0h, B0h, c00, 0, 0, 0);
    c01 = __builtin_amdgcn_mfma_f32_16x16x32_bf16(A0h, B1h, c01, 0, 0, 0);
    c10 = __builtin_amdgcn_mfma_f32_16x16x32_bf16(A1h, B0h, c10, 0, 0, 0);
    c11 = __builtin_amdgcn_mfma_f32_16x16x32_bf16(A1h, B1h, c11, 0, 0, 0);
    c00 = __builtin_amdgcn_mfma_f32_16x16x32_bf16(A0h, B0l, c00, 0, 0, 0);
    c01 = __builtin_amdgcn_mfma_f32_16x16x32_bf16(A0h, B1l, c01, 0, 0, 0);
    c10 = __builtin_amdgcn_mfma_f32_16x16x32_bf16(A1h, B0l, c10, 0, 0, 0);
    c11 = __builtin_amdgcn_mfma_f32_16x16x32_bf16(A1h, B1l, c11, 0, 0, 0);
    c00 = __builtin_amdgcn_mfma_f32_16x16x32_bf16(A0l, B0h, c00, 0, 0, 0);
    c01 = __builtin_amdgcn_mfma_f32_16x16x32_bf16(A0l, B1h, c01, 0, 0, 0);
    c10 = __builtin_amdgcn_mfma_f32_16x16x32_bf16(A1l, B0h, c10, 0, 0, 0);
    c11 = __builtin_amdgcn_mfma_f32_16x16x32_bf16(A1l, B1h, c11, 0, 0, 0);
  }

  int orow = (lane >> 4) << 2;
  int col0 = j0 + lr, col1 = j0 + 16 + lr;
  if (KS == 1) {
    float bb0 = bias[col0], bb1 = bias[col1];
    #pragma unroll
    for (int r = 0; r < 4; r++) {
      int row0 = i0 + orow + r, row1 = row0 + 16;
      C[(size_t)row0*N + col0] = c00[r] + bb0;
      C[(size_t)row0*N + col1] = c01[r] + bb1;
      C[(size_t)row1*N + col0] = c10[r] + bb0;
      C[(size_t)row1*N + col1] = c11[r] + bb1;
    }
  } else {
    float* dst = Cpart + (size_t)blockIdx.z * M * N;
    #pragma unroll
    for (int r = 0; r < 4; r++) {
      int row0 = i0 + orow + r, row1 = row0 + 16;
      dst[(size_t)row0*N + col0] = c00[r];
      dst[(size_t)row0*N + col1] = c01[r];
      dst[(size_t)row1*N + col0] = c10[r];
      dst[(size_t)row1*N + col1] = c11[r];
    }
  }
}

__global__ void k_reduce_bias(const float* __restrict__ part, const float* __restrict__ bias,
                              float* __restrict__ out, int MN, int N, int KS) {
  int e = blockIdx.x * 256 + threadIdx.x;
  if (e >= MN) return;
  float s = bias[e % N];
  for (int z = 0; z < KS; z++) s += part[(size_t)z*MN + e];
  out[e] = s;
}

// ---------------------------------------------------------------- fused feature-build + logits MFMA
__global__ __launch_bounds__(256) void k_feat_logits(
    const float* __restrict__ C1, const float* __restrict__ rot,
    const float* __restrict__ trans, const float* __restrict__ gamma,
    const float* __restrict__ w_c, const float* __restrict__ w_l,
    float* __restrict__ S) {
  __shared__ u16 Ash[64][72], Asl[64][72], Bsh[64][72], Bsl[64][72];  // 36.9 KB
  int h = blockIdx.z;
  int i0 = blockIdx.y * 64, j0 = blockIdx.x * 64;
  int t = threadIdx.x;

  if (t < 128) {
    int row = t & 63, side = t >> 6;      // side 0 = A (query), 1 = B (key)
    int gi = (side ? j0 : i0) + row;
    float R[9], tr[3];
    #pragma unroll
    for (int r = 0; r < 9; r++) R[r] = rot[(size_t)gi*9 + r];
    #pragma unroll
    for (int r = 0; r < 3; r++) tr[r] = trans[(size_t)gi*3 + r];
    float sc = w_c[0] * rsqrtf(32.f);
    float gp = gamma[h] * w_l[0];
    u16 (*Fh)[72] = side ? Bsh : Ash;
    u16 (*Fl)[72] = side ? Bsl : Asl;
    const float* qk = C1 + (size_t)gi*NPP + (side ? 384 : 0) + h*32;
    u16 h_, l_;
    #pragma unroll 8
    for (int d = 0; d < 32; d++) {
      float v = side ? qk[d] : sc*qk[d];
      split_bf16(v, h_, l_); Fh[row][d] = h_; Fl[row][d] = l_;
    }
    const float* pp = C1 + (size_t)gi*NPP + (side ? 1296 : 1152) + h*12;
    float ss = 0.f;
    #pragma unroll
    for (int p = 0; p < 4; p++) {
      float x = pp[p*3], y = pp[p*3+1], z = pp[p*3+2];
      #pragma unroll
      for (int r = 0; r < 3; r++) {
        float g = fmaf(R[r*3],x, fmaf(R[r*3+1],y, fmaf(R[r*3+2],z, tr[r])));
        float v = side ? g : gp*g;
        split_bf16(v, h_, l_); Fh[row][32+p*3+r] = h_; Fl[row][32+p*3+r] = l_;
        ss = fmaf(g,g,ss);
      }
    }
    float c44 = side ? 1.f : -0.5f*gp*ss;
    float c45 = side ? -0.5f*gp*ss : 1.f;
    split_bf16(c44, h_, l_); Fh[row][44] = h_; Fl[row][44] = l_;
    split_bf16(c45, h_, l_); Fh[row][45] = h_; Fl[row][45] = l_;
    #pragma unroll
    for (int d = 46; d < 64; d++) { Fh[row][d] = 0; Fl[row][d] = 0; }
  }
  __syncthreads();

  int lane = t & 63, wave = t >> 6, wr = wave >> 1, wc = wave & 1;
  int lr = lane & 15, lk = (lane >> 4) << 3;
  f32x4 c00 = {0.f,0.f,0.f,0.f}, c01 = c00, c10 = c00, c11 = c00;
  #pragma unroll
  for (int ks = 0; ks < 64; ks += 32) {
    bf16x8 A0h = *(const bf16x8*)&Ash[wr*32 + lr][ks + lk];
    bf16x8 A1h = *(const bf16x8*)&Ash[wr*32 + 16 + lr][ks + lk];
    bf16x8 B0h = *(const bf16x8*)&Bsh[wc*32 + lr][ks + lk];
    bf16x8 B1h = *(const bf16x8*)&Bsh[wc*32 + 16 + lr][ks + lk];
    bf16x8 A0l = *(const bf16x8*)&Asl[wr*32 + lr][ks + lk];
    bf16x8 A1l = *(const bf16x8*)&Asl[wr*32 + 16 + lr][ks + lk];
    bf16x8 B0l = *(const bf16x8*)&Bsl[wc*32 + lr][ks + lk];
    bf16x8 B1l = *(const bf16x8*)&Bsl[wc*32 + 16 + lr][ks + lk];
    c00 = __builtin_amdgcn_mfma_f32_16x16x32_bf16(A0h, B0h, c00, 0, 0, 0);
    c01 = __builtin_amdgcn_mfma_f32_16x16x32_bf16(A0h, B1h, c01, 0, 0, 0);
    c10 = __builtin_amdgcn_mfma_f32_16x16x32_bf16(A1h, B0h, c10, 0, 0, 0);
    c11 = __builtin_amdgcn_mfma_f32_16x16x32_bf16(A1h, B1h, c11, 0, 0, 0);
    c00 = __builtin_amdgcn_mfma_f32_16x16x32_bf16(A0h, B0l, c00, 0, 0, 0);
    c01 = __builtin_amdgcn_mfma_f32_16x16x32_bf16(A0h, B1l, c01, 0, 0, 0);
    c10 = __builtin_amdgcn_mfma_f32_16x16x32_bf16(A1h, B0l, c10, 0, 0, 0);
    c11 = __builtin_amdgcn_mfma_f32_16x16x32_bf16(A1h, B1l, c11, 0, 0, 0);
    c00 = __builtin_amdgcn_mfma_f32_16x16x32_bf16(A0l, B0h, c00, 0, 0, 0);
    c01 = __builtin_amdgcn_mfma_f32_16x16x32_bf16(A0l, B1h, c01, 0, 0, 0);
    c10 = __builtin_amdgcn_mfma_f32_16x16x32_bf16(A1l, B0h, c10, 0, 0, 0);
    c11 = __builtin_amdgcn_mfma_f32_16x16x32_bf16(A1l, B1h, c11, 0, 0, 0);
  }

  int orow = (lane >> 4) << 2;
  int col0 = j0 + wc*32 + lr, col1 = col0 + 16;
  int rbase = i0 + wr*32 + orow;
  #pragma unroll
  for (int r = 0; r < 4; r++) {
    S[((size_t)h*LQ + rbase + r)*LQ + col0]      = c00[r];
    S[((size_t)h*LQ + rbase + r)*LQ + col1]      = c01[r];
    S[((size_t)h*LQ + rbase + 16 + r)*LQ + col0] = c10[r];
    S[((size_t)h*LQ + rbase + 16 + r)*LQ + col1] = c11[r];
  }
}

// ---------------------------------------------------------------- Vt builder: [NH][64][LQ] split-bf16
// rows 0..31 = v, 32..55 = rotated vg, 56..63 = 0. i-contiguous writes = coalesced.
__global__ __launch_bounds__(256) void k_vt(
    const float* __restrict__ C1, const float* __restrict__ rot,
    const float* __restrict__ trans,
    u16* __restrict__ Vth, u16* __restrict__ Vtl) {
  int h = blockIdx.x;
  int i = blockIdx.y * 256 + threadIdx.x;
  float R[9], tr[3];
  #pragma unroll
  for (int r = 0; r < 9; r++) R[r] = rot[(size_t)i*9 + r];
  #pragma unroll
  for (int r = 0; r < 3; r++) tr[r] = trans[(size_t)i*3 + r];
  const float* vrow = C1 + (size_t)i*NPP + 768 + h*32;
  const float* prow = C1 + (size_t)i*NPP + 1440 + h*24;
  u16 h_, l_;
  #pragma unroll 8
  for (int n = 0; n < 32; n++) {
    split_bf16(vrow[n], h_, l_);
    Vth[((size_t)h*64 + n)*LQ + i] = h_;
    Vtl[((size_t)h*64 + n)*LQ + i] = l_;
  }
  #pragma unroll
  for (int p = 0; p < 8; p++) {
    float x = prow[p*3], y = prow[p*3+1], z = prow[p*3+2];
    #pragma unroll
    for (int r = 0; r < 3; r++) {
      float g = fmaf(R[r*3],x, fmaf(R[r*3+1],y, fmaf(R[r*3+2],z, tr[r])));
      split_bf16(g, h_, l_);
      Vth[((size_t)h*64 + 32 + p*3 + r)*LQ + i] = h_;
      Vtl[((size_t)h*64 + 32 + p*3 + r)*LQ + i] = l_;
    }
  }
  #pragma unroll
  for (int n = 56; n < 64; n++) {
    Vth[((size_t)h*64 + n)*LQ + i] = 0;
    Vtl[((size_t)h*64 + n)*LQ + i] = 0;
  }
}

// ---------------------------------------------------------------- per-i pair stage, DMA double-buffered:
// one block per i. LDS tiles filled by global_load_lds (source-swizzled k4^=row&7
// so linear DMA dest gives conflict-free reads both by-row and by-column).
// RACE-FIX vs r5: explicit `s_waitcnt vmcnt(0)` before each barrier that
// publishes a DMA-filled buffer (the compiler's implicit drain before s_barrier
// is not a guaranteed contract — m152 lesson).
__global__ __launch_bounds__(256) void k_pair(
    const float* __restrict__ pair, const float* __restrict__ WpbT,
    const float* __restrict__ bpb, const float* __restrict__ mask,
    float* S, float* __restrict__ scs_g,
    u16* __restrict__ combh, u16* __restrict__ combl) {
  __shared__ float tile[2][TJC*DPAIR];   // 64 KB, swizzled
  __shared__ float wt[NH*TJC];           // 3 KB
  __shared__ float msc[NC][NH], ssc[NC][NH];
  __shared__ float rfac[NH], dinv[NH];
  int i = blockIdx.x, t = threadIdx.x;
  int lane = t & 63, wave = t >> 6;
  int j = lane;
  int h0 = wave * 3;                     // softmax wave owns heads h0..h0+2
  int dg = t & 31, strip = t >> 5, jb = strip*8;

  const float* prow = pair + (size_t)i*LQ*DPAIR;
  float b0 = bpb[h0], b1 = bpb[h0+1], b2 = bpb[h0+2];
  float mi = mask[i];
  const float* w0p = WpbT + (size_t)(h0+0)*DPAIR;
  const float* w1p = WpbT + (size_t)(h0+1)*DPAIR;
  const float* w2p = WpbT + (size_t)(h0+2)*DPAIR;

  float4 acc[NH];
  #pragma unroll
  for (int h = 0; h < NH; h++) acc[h] = make_float4(0.f,0.f,0.f,0.f);
  float mrun[3] = {-3.0e38f, -3.0e38f, -3.0e38f};

  // DMA one 64x128 chunk into buf; 8 instrs/wave, 1KB each (2 rows per instr)
  auto dma = [&](int c, int buf) {
    #pragma unroll
    for (int u = 0; u < 8; u++) {
      int seg = wave*8 + u;
      int F = seg*64 + lane;             // float4 index in tile
      int row = F >> 5, k4s = F & 31;
      int k4 = k4s ^ (row & 7);          // inverse swizzle on source
      const float* src = prow + (size_t)(c*TJC + row)*DPAIR + k4*4;
      async_copy16(src, &tile[buf][seg*256]);
    }
  };

  dma(0, 0);
  asm volatile("s_waitcnt vmcnt(0)" ::: "memory");   // DMA landed in LDS
  __syncthreads();                                    // publish tile0
  int cur = 0;

  for (int c = 0; c < NC; c++) {
    if (c < NC-1) dma(c+1, cur^1);        // overlaps phases A+softmax+C below
    int j0 = c*TJC;
    // phase A: logits = S + bias + pair-bias GEMV from swizzled LDS tile
    float l0 = S[((size_t)(h0+0)*LQ + i)*LQ + j0 + j] + b0;
    float l1 = S[((size_t)(h0+1)*LQ + i)*LQ + j0 + j] + b1;
    float l2 = S[((size_t)(h0+2)*LQ + i)*LQ + j0 + j] + b2;
    {
      float a0 = 0.f, a1 = 0.f, a2 = 0.f;
      #pragma unroll 8
      for (int kk = 0; kk < 32; kk++) {
        float4 pv = *(const float4*)&tile[cur][(j*32 + (kk ^ (j & 7)))*4];
        float4 w0 = *(const float4*)(w0p + kk*4);
        float4 w1 = *(const float4*)(w1p + kk*4);
        float4 w2 = *(const float4*)(w2p + kk*4);
        a0 = fmaf(pv.x,w0.x, fmaf(pv.y,w0.y, fmaf(pv.z,w0.z, fmaf(pv.w,w0.w, a0))));
        a1 = fmaf(pv.x,w1.x, fmaf(pv.y,w1.y, fmaf(pv.z,w1.z, fmaf(pv.w,w1.w, a1))));
        a2 = fmaf(pv.x,w2.x, fmaf(pv.y,w2.y, fmaf(pv.z,w2.z, fmaf(pv.w,w2.w, a2))));
      }
      l0 += a0; l1 += a1; l2 += a2;
      bool dead = (mi * mask[j0 + j] <= 0.f);
      if (dead) { l0 = -1e9f; l1 = -1e9f; l2 = -1e9f; }
    }
    // chunk softmax + running-max bookkeeping (lane-uniform after reduce)
    #pragma unroll
    for (int q = 0; q < 3; q++) {
      float lv = (q==0) ? l0 : (q==1) ? l1 : l2;
      float m = lv;
      #pragma unroll
      for (int o = 32; o > 0; o >>= 1) m = fmaxf(m, __shfl_xor(m, o, 64));
      float w = __expf(lv - m);
      float sm = w;
      #pragma unroll
      for (int o = 32; o > 0; o >>= 1) sm += __shfl_xor(sm, o, 64);
      float mnew = fmaxf(mrun[q], m);
      float f  = __expf(m - mnew);
      float rf = __expf(mrun[q] - mnew);
      mrun[q] = mnew;
      wt[(h0+q)*TJC + j] = w * f;
      S[((size_t)(h0+q)*LQ + i)*LQ + j0 + j] = w;
      if (j == 0) { msc[c][h0+q] = m; ssc[c][h0+q] = sm; rfac[h0+q] = rf; }
    }
    __syncthreads();   // wt + rfac ready
    // phase C: online-rescaled accumulation from the same tile
    {
      float4 pv[8];
      #pragma unroll
      for (int q = 0; q < 8; q++) {
        int row = jb + q;
        pv[q] = *(const float4*)&tile[cur][(row*32 + (dg ^ (row & 7)))*4];
      }
      #pragma unroll
      for (int h = 0; h < NH; h++) {
        float rf = rfac[h];
        float4 w0 = *(const float4*)&wt[h*TJC + jb];
        float4 w1 = *(const float4*)&wt[h*TJC + jb + 4];
        float wq[8] = {w0.x,w0.y,w0.z,w0.w,w1.x,w1.y,w1.z,w1.w};
        float4 a = acc[h];
        a.x *= rf; a.y *= rf; a.z *= rf; a.w *= rf;
        #pragma unroll
        for (int q = 0; q < 8; q++) {
          a.x = fmaf(wq[q], pv[q].x, a.x);
          a.y = fmaf(wq[q], pv[q].y, a.y);
          a.z = fmaf(wq[q], pv[q].z, a.z);
          a.w = fmaf(wq[q], pv[q].w, a.w);
        }
        acc[h] = a;
      }
    }
    asm volatile("s_waitcnt vmcnt(0)" ::: "memory");  // next-buf DMA landed
    __syncthreads();   // publish tile[cur^1]; tile[cur] reads done
    cur ^= 1;
  }

  // denominators + scs_g (lane 0 of each softmax wave owns its 3 heads)
  if (j == 0) {
    #pragma unroll
    for (int q = 0; q < 3; q++) {
      float M = mrun[q];
      float den = 0.f;
      #pragma unroll
      for (int c = 0; c < NC; c++) den += ssc[c][h0+q] * __expf(msc[c][h0+q] - M);
      float inv = 1.f / den;
      dinv[h0+q] = inv;
      #pragma unroll
      for (int c = 0; c < NC; c++)
        scs_g[((size_t)i*NH + h0+q)*NC + c] = __expf(msc[c][h0+q] - M) * inv;
    }
  }

  // cross-strip reduction (scratch = tile[0]), then comb write
  float4* red4 = (float4*)&tile[0][0];   // 1536 float4 <= 2048 cap
  float4 tot[2];
  tot[0] = make_float4(0.f,0.f,0.f,0.f);
  tot[1] = make_float4(0.f,0.f,0.f,0.f);
  #pragma unroll
  for (int half = 0; half < 2; half++) {
    if ((strip >> 2) == half) {
      #pragma unroll
      for (int h = 0; h < NH; h++)
        red4[(((strip & 3)*NH) + h)*32 + dg] = acc[h];
    }
    __syncthreads();
    for (int e = t, u = 0; e < NH*32; e += 256, u++) {
      int rh = e >> 5, rd = e & 31;
      #pragma unroll
      for (int s4 = 0; s4 < 4; s4++) {
        float4 v = red4[((s4*NH) + rh)*32 + rd];
        tot[u].x += v.x; tot[u].y += v.y; tot[u].z += v.z; tot[u].w += v.w;
      }
    }
    __syncthreads();
  }
  for (int e = t, u = 0; e < NH*32; e += 256, u++) {
    int rh = e >> 5, rd = e & 31;
    float inv = dinv[rh];
    size_t dst = (size_t)i*2304 + 768 + rh*DPAIR + rd*4;
    u16 h_, l_;
    split_bf16(tot[u].x * inv, h_, l_); combh[dst+0] = h_; combl[dst+0] = l_;
    split_bf16(tot[u].y * inv, h_, l_); combh[dst+1] = h_; combl[dst+1] = l_;
    split_bf16(tot[u].z * inv, h_, l_); combh[dst+2] = h_; combl[dst+2] = l_;
    split_bf16(tot[u].w * inv, h_, l_); combh[dst+3] = h_; combl[dst+3] = l_;
  }
}

// ---------------------------------------------------------------- attn @ [v|vg] via MFMA, split-K=4 -> psum
// A-fragments built on the fly from S (f32, unnormalized) x scs_g -> split bf16.
// B-fragments direct from Vt. No LDS.
__global__ __launch_bounds__(256) void k_attn_mfma(
    const float* __restrict__ S, const float* __restrict__ scs_g,
    const u16* __restrict__ Vth, const u16* __restrict__ Vtl,
    float* __restrict__ psum) {
  int t = threadIdx.x;
  int lane = t & 63, wave = t >> 6;
  int wr = wave >> 1, wc = wave & 1;
  int z = blockIdx.x;                 // split-K
  int i0 = blockIdx.y * 64 + wr * 32;
  int h = blockIdx.z;
  int n0 = wc * 32;
  int lr = lane & 15, lk = (lane >> 4) << 3;

  const float* a0p = S + ((size_t)h*LQ + i0 + lr)*LQ + z*128 + lk;
  const float* a1p = a0p + (size_t)16*LQ;
  const float* s0p = scs_g + ((size_t)(i0 + lr)*NH + h)*NC + z*2;
  const float* s1p = scs_g + ((size_t)(i0 + 16 + lr)*NH + h)*NC + z*2;
  const u16* b0h = Vth + ((size_t)h*64 + n0 + lr)*LQ + z*128 + lk;
  const u16* b1h = b0h + (size_t)16*LQ;
  const u16* b0l = Vtl + ((size_t)h*64 + n0 + lr)*LQ + z*128 + lk;
  const u16* b1l = b0l + (size_t)16*LQ;

  f32x4 c00 = {0.f,0.f,0.f,0.f}, c01 = c00, c10 = c00, c11 = c00;
  #pragma unroll
  for (int k = 0; k < 128; k += 32) {
    int cc = (k >= 64) ? 1 : 0;
    float sc0 = s0p[cc], sc1 = s1p[cc];
    float4 av00 = *(const float4*)(a0p + k);
    float4 av01 = *(const float4*)(a0p + k + 4);
    float4 av10 = *(const float4*)(a1p + k);
    float4 av11 = *(const float4*)(a1p + k + 4);
    float a0v[8] = {av00.x,av00.y,av00.z,av00.w,av01.x,av01.y,av01.z,av01.w};
    float a1v[8] = {av10.x,av10.y,av10.z,av10.w,av11.x,av11.y,av11.z,av11.w};
    bf16x8 A0h = {}, A0l = {}, A1h = {}, A1l = {};
    #pragma unroll
    for (int e = 0; e < 8; e++) {
      u16 hh, ll;
      split_bf16(a0v[e]*sc0, hh, ll);
      A0h[e] = (short)hh; A0l[e] = (short)ll;
      split_bf16(a1v[e]*sc1, hh, ll);
      A1h[e] = (short)hh; A1l[e] = (short)ll;
    }
    bf16x8 B0h = *(const bf16x8*)(b0h + k);
    bf16x8 B1h = *(const bf16x8*)(b1h + k);
    bf16x8 B0l = *(const bf16x8*)(b0l + k);
    bf16x8 B1l = *(const bf16x8*)(b1l + k);
    c00 = __builtin_amdgcn_mfma_f32_16x16x32_bf16(A0h, B0h, c00, 0, 0, 0);
    c01 = __builtin_amdgcn_mfma_f32_16x16x32_bf16(A0h, B1h, c01, 0, 0, 0);
    c10 = __builtin_amdgcn_mfma_f32_16x16x32_bf16(A1h, B0h, c10, 0, 0, 0);
    c11 = __builtin_amdgcn_mfma_f32_16x16x32_bf16(A1h, B1h, c11, 0, 0, 0);
    c00 = __builtin_amdgcn_mfma_f32_16x16x32_bf16(A0h, B0l, c00, 0, 0, 0);
    c01 = __builtin_amdgcn_mfma_f32_16x16x32_bf16(A0h, B1l, c01, 0, 0, 0);
    c10 = __builtin_amdgcn_mfma_f32_16x16x32_bf16(A1h, B0l, c10, 0, 0, 0);
    c11 = __builtin_amdgcn_mfma_f32_16x16x32_bf16(A1h, B1l, c11, 0, 0, 0);
    c00 = __builtin_amdgcn_mfma_f32_16x16x32_bf16(A0l, B0h, c00, 0, 0, 0);
    c01 = __builtin_amdgcn_mfma_f32_16x16x32_bf16(A0l, B1h, c01, 0, 0, 0);
    c10 = __builtin_amdgcn_mfma_f32_16x16x32_bf16(A1l, B0h, c10, 0, 0, 0);
    c11 = __builtin_amdgcn_mfma_f32_16x16x32_bf16(A1l, B1h, c11, 0, 0, 0);
  }

  int orow = (lane >> 4) << 2;
  int col0 = n0 + lr, col1 = n0 + 16 + lr;
  #pragma unroll
  for (int r = 0; r < 4; r++) {
    int row0 = i0 + orow + r, row1 = row0 + 16;
    psum[(((size_t)z*LQ + row0)*NH + h)*64 + col0] = c00[r];
    psum[(((size_t)z*LQ + row0)*NH + h)*64 + col1] = c01[r];
    psum[(((size_t)z*LQ + row1)*NH + h)*64 + col0] = c10[r];
    psum[(((size_t)z*LQ + row1)*NH + h)*64 + col1] = c11[r];
  }
}

// ---------------------------------------------------------------- fused av_reduce + pts_feat -> comb (split-bf16)
__global__ void k_avpts(const float* __restrict__ psum, const float* __restrict__ rot,
                        const float* __restrict__ trans,
                        u16* __restrict__ combh, u16* __restrict__ combl) {
  int idx = blockIdx.x * 256 + threadIdx.x;
  if (idx >= LQ*NH*40) return;
  int w = idx % 40; int ih = idx / 40; int h = ih % NH; int i = ih / NH;
  size_t base = ((size_t)i*NH + h)*64;
  u16 h_, l_;
  if (w < 32) {
    float s = 0.f;
    for (int z = 0; z < 4; z++) s += psum[(size_t)z*LQ*NH*64 + base + w];
    split_bf16(s, h_, l_);
    combh[(size_t)i*2304 + h*32 + w] = h_;
    combl[(size_t)i*2304 + h*32 + w] = l_;
  } else {
    int p = w - 32;
    float g[3];
    #pragma unroll
    for (int r = 0; r < 3; r++) {
      int n = 32 + p*3 + r;
      float s = 0.f;
      for (int z = 0; z < 4; z++) s += psum[(size_t)z*LQ*NH*64 + base + n];
      g[r] = s;
    }
    const float* R = rot + (size_t)i*9;
    const float* tr = trans + (size_t)i*3;
    float x = g[0]-tr[0], y = g[1]-tr[1], z = g[2]-tr[2];
    float lx = fmaf(R[0],x, fmaf(R[3],y, R[6]*z));
    float ly = fmaf(R[1],x, fmaf(R[4],y, R[7]*z));
    float lz = fmaf(R[2],x, fmaf(R[5],y, R[8]*z));
    float nrm = sqrtf(fmaf(lx,lx, fmaf(ly,ly, lz*lz)));
    size_t dst = (size_t)i*2304 + 384 + (h*8 + p)*4;
    split_bf16(nrm, h_, l_); combh[dst+0] = h_; combl[dst+0] = l_;
    split_bf16(lx,  h_, l_); combh[dst+1] = h_; combl[dst+1] = l_;
    split_bf16(ly,  h_, l_); combh[dst+2] = h_; combl[dst+2] = l_;
    split_bf16(lz,  h_, l_); combh[dst+3] = h_; combl[dst+3] = l_;
  }
}

// ================================================================ launcher
extern "C" void kernel_launch(void* const* d_in, const int* in_sizes, int n_in,
                              void* d_out, int out_size, void* d_ws, size_t ws_size,
                              hipStream_t stream) {
  const float* single = (const float*)d_in[0];
  const float* pair   = (const float*)d_in[1];
  const float* rot    = (const float*)d_in[2];
  const float* trans  = (const float*)d_in[3];
  const float* mask   = (const float*)d_in[4];
  const float* ln_w   = (const float*)d_in[5];
  const float* ln_b   = (const float*)d_in[6];
  const float* Wq     = (const float*)d_in[7];
  const float* bq     = (const float*)d_in[8];
  const float* Wk     = (const float*)d_in[9];
  const float* bk     = (const float*)d_in[10];
  const float* Wv     = (const float*)d_in[11];
  const float* bv     = (const float*)d_in[12];
  const float* Wqp    = (const float*)d_in[13];
  const float* bqp    = (const float*)d_in[14];
  const float* Wkp    = (const float*)d_in[15];
  const float* bkp    = (const float*)d_in[16];
  const float* Wvp    = (const float*)d_in[17];
  const float* bvp    = (const float*)d_in[18];
  const float* Wpb    = (const float*)d_in[19];
  const float* bpb    = (const float*)d_in[20];
  const float* Wo     = (const float*)d_in[21];
  const float* bo     = (const float*)d_in[22];
  const float* w_c    = (const float*)d_in[23];
  const float* w_l    = (const float*)d_in[24];
  const float* gamma  = (const float*)d_in[25];
  float* out = (float*)d_out;

  float* p = (float*)d_ws;
  auto alloc = [&](size_t n) { float* r = p; p += n; return r; };
  u16* WcatTh = (u16*)alloc((size_t)NPP*DS/2);
  u16* WcatTl = (u16*)alloc((size_t)NPP*DS/2);
  u16* snh    = (u16*)alloc((size_t)LQ*DS/2);
  u16* snl    = (u16*)alloc((size_t)LQ*DS/2);
  u16* WoTh   = (u16*)alloc((size_t)DS*2304/2);
  u16* WoTl   = (u16*)alloc((size_t)DS*2304/2);
  u16* combh  = (u16*)alloc((size_t)LQ*2304/2);
  u16* combl  = (u16*)alloc((size_t)LQ*2304/2);
  u16* Vth    = (u16*)alloc((size_t)NH*64*LQ/2);
  u16* Vtl    = (u16*)alloc((size_t)NH*64*LQ/2);
  float* bcat    = alloc(NPP);
  float* WpbT    = alloc((size_t)NH*DPAIR);
  float* C1      = alloc((size_t)LQ*NPP);
  float* S       = alloc((size_t)NH*LQ*LQ);
  float* scs_g   = alloc((size_t)LQ*NH*NC);
  float* psum    = alloc((size_t)4*LQ*NH*64);
  float* outpart = alloc((size_t)8*LQ*DS);

  k_prep<<<dim3(897), 256, 0, stream>>>(
      Wq, Wk, Wv, Wqp, Wkp, Wvp, bq, bk, bv, bqp, bkp, bvp, Wpb, Wo,
      single, ln_w, ln_b, WcatTh, WcatTl, bcat, WpbT, WoTh, WoTl, snh, snl);
  k_gemm_mfma<<<dim3(NPP/64, LQ/64, 1), 256, 0, stream>>>(
      snh, snl, WcatTh, WcatTl, bcat, C1, nullptr, LQ, NPP, DS);
  k_feat_logits<<<dim3(LQ/64, LQ/64, NH), 256, 0, stream>>>(
      C1, rot, trans, gamma, w_c, w_l, S);
  k_vt<<<dim3(NH, LQ/256), 256, 0, stream>>>(C1, rot, trans, Vth, Vtl);
  k_pair<<<dim3(LQ), 256, 0, stream>>>(
      pair, WpbT, bpb, mask, S, scs_g, combh, combl);
  k_attn_mfma<<<dim3(4, LQ/64, NH), 256, 0, stream>>>(
      S, scs_g, Vth, Vtl, psum);
  k_avpts<<<dim3((LQ*NH*40 + 255)/256), 256, 0, stream>>>(
      psum, rot, trans, combh, combl);
  k_gemm_mfma<<<dim3(DS/64, LQ/64, 8), 256, 0, stream>>>(
      combh, combl, WoTh, WoTl, nullptr, nullptr, outpart, LQ, DS, 2304);
  k_reduce_bias<<<dim3((LQ*DS + 255)/256), 256, 0, stream>>>(outpart, bo, out, LQ*DS, DS, 8);
}

// Round 7
// 347.179 us; speedup vs baseline: 1.2126x; 1.0833x over previous
//
#include <hip/hip_runtime.h>
#include <math.h>

// Problem constants
#define LQ    512
#define DS    384
#define DPAIR 128
#define NH    12
#define NPP   1792   // padded projection width
#define TJC   64     // j-chunk for pair kernel
#define NC    8      // number of j-chunks (LQ/TJC)

typedef unsigned short u16;
typedef unsigned int   u32;
typedef __attribute__((ext_vector_type(8))) short bf16x8;  // 8 bf16 in 4 VGPRs
typedef __attribute__((ext_vector_type(4))) float f32x4;

// round-to-nearest-even f32 -> bf16 bits
__device__ inline u16 bf16_rne(float x) {
  u32 u = __float_as_uint(x);
  u32 r = (u + 0x7FFFu + ((u >> 16) & 1u)) >> 16;
  return (u16)r;
}
// split x ~= hi + lo (both bf16); residual ~2^-17 relative
__device__ inline void split_bf16(float x, u16& h, u16& l) {
  u16 hb = bf16_rne(x);
  float hf = __uint_as_float(((u32)hb) << 16);
  h = hb;
  l = bf16_rne(x - hf);
}

// ---------------------------------------------------------------- fused prep:
// blocks 0..167   : Wcat transpose+split tiles -> WcatT [NPP][DS] bf16 hi/lo
// block  168      : bcat + WpbT
// blocks 169..384 : Wo transpose+split tiles   -> WoT [384][2304] bf16 hi/lo
// blocks 385..896 : layernorm rows -> sn split-bf16
__global__ __launch_bounds__(256) void k_prep(
    const float* __restrict__ Wq, const float* __restrict__ Wk,
    const float* __restrict__ Wv, const float* __restrict__ Wqp,
    const float* __restrict__ Wkp, const float* __restrict__ Wvp,
    const float* __restrict__ bq, const float* __restrict__ bk,
    const float* __restrict__ bv, const float* __restrict__ bqp,
    const float* __restrict__ bkp, const float* __restrict__ bvp,
    const float* __restrict__ Wpb, const float* __restrict__ Wo,
    const float* __restrict__ xs, const float* __restrict__ ln_w,
    const float* __restrict__ ln_b,
    u16* __restrict__ Wth, u16* __restrict__ Wtl,
    float* __restrict__ bcat, float* __restrict__ WpbT,
    u16* __restrict__ WoTh, u16* __restrict__ WoTl,
    u16* __restrict__ snh, u16* __restrict__ snl) {
  __shared__ u16 sh_hi[64][66], sh_lo[64][66];   // stride 66 -> conflict-free
  int blk = blockIdx.x, t = threadIdx.x;
  if (blk < 168) {
    int kb = blk / 28, cb = blk % 28;
    int k0 = kb * 64, c0 = cb * 64;
    for (int e = t; e < 4096; e += 256) {
      int rr = e >> 6, cc = e & 63;
      int k = k0 + rr, c = c0 + cc;
      float v = 0.f;
      if (c < 384)       v = Wq[k*384 + c];
      else if (c < 768)  v = Wk[k*384 + c-384];
      else if (c < 1152) v = Wv[k*384 + c-768];
      else if (c < 1296) v = Wqp[k*144 + c-1152];
      else if (c < 1440) v = Wkp[k*144 + c-1296];
      else if (c < 1728) v = Wvp[k*288 + c-1440];
      u16 h_, l_; split_bf16(v, h_, l_);
      sh_hi[rr][cc] = h_; sh_lo[rr][cc] = l_;
    }
    __syncthreads();
    for (int e = t; e < 4096; e += 256) {
      int cc = e >> 6, kk = e & 63;
      Wth[(size_t)(c0+cc)*DS + k0 + kk] = sh_hi[kk][cc];
      Wtl[(size_t)(c0+cc)*DS + k0 + kk] = sh_lo[kk][cc];
    }
  } else if (blk == 168) {
    for (int e = t; e < NPP + NH*DPAIR; e += 256) {
      if (e < NPP) {
        int c = e;
        float v = 0.f;
        if (c < 384)       v = bq[c];
        else if (c < 768)  v = bk[c-384];
        else if (c < 1152) v = bv[c-768];
        else if (c < 1296) v = bqp[c-1152];
        else if (c < 1440) v = bkp[c-1296];
        else if (c < 1728) v = bvp[c-1440];
        bcat[c] = v;
      } else {
        int e2 = e - NPP;
        int k = e2 / NH, h = e2 % NH;
        WpbT[h*DPAIR + k] = Wpb[e2];
      }
    }
  } else if (blk < 385) {
    int idx = blk - 169;
    int kt = idx % 36, nt = idx / 36;      // Wo is [2304][384]
    int k0 = kt * 64, n0 = nt * 64;
    for (int e = t; e < 4096; e += 256) {
      int rr = e >> 6, cc = e & 63;
      float v = Wo[(size_t)(k0+rr)*384 + n0 + cc];
      u16 h_, l_; split_bf16(v, h_, l_);
      sh_hi[rr][cc] = h_; sh_lo[rr][cc] = l_;
    }
    __syncthreads();
    for (int e = t; e < 4096; e += 256) {
      int cc = e >> 6, kk = e & 63;
      WoTh[(size_t)(n0+cc)*2304 + k0 + kk] = sh_hi[kk][cc];
      WoTl[(size_t)(n0+cc)*2304 + k0 + kk] = sh_lo[kk][cc];
    }
  } else {
    // layernorm row, 256 threads covering 384 elements
    int i = blk - 385;
    float* red = (float*)&sh_hi[0][0];
    float a0 = xs[i*DS + t];
    float a1 = (t < 128) ? xs[i*DS + 256 + t] : 0.f;
    red[t] = a0 + a1; __syncthreads();
    for (int s = 128; s > 0; s >>= 1) { if (t < s) red[t] += red[t+s]; __syncthreads(); }
    float mu = red[0] * (1.f/384.f);
    __syncthreads();
    float d0 = a0 - mu, d1 = (t < 128) ? (a1 - mu) : 0.f;
    red[t] = d0*d0 + d1*d1; __syncthreads();
    for (int s = 128; s > 0; s >>= 1) { if (t < s) red[t] += red[t+s]; __syncthreads(); }
    float rstd = rsqrtf(red[0] * (1.f/384.f) + 1e-5f);
    u16 h_, l_;
    float y0 = d0*rstd*ln_w[t] + ln_b[t];
    split_bf16(y0, h_, l_); snh[i*DS + t] = h_; snl[i*DS + t] = l_;
    if (t < 128) {
      float y1 = d1*rstd*ln_w[256+t] + ln_b[256+t];
      split_bf16(y1, h_, l_); snh[i*DS + 256 + t] = h_; snl[i*DS + 256 + t] = l_;
    }
  }
}

// ---------------------------------------------------------------- MFMA GEMM: C[M][N] = A[M][K] @ Bt[N][K]^T
// 3-term compensated bf16 (AhBh + AhBl + AlBh), f32 accumulate -> ~f32 accuracy.
__global__ __launch_bounds__(256) void k_gemm_mfma(
    const u16* __restrict__ Ah, const u16* __restrict__ Al,
    const u16* __restrict__ Bth, const u16* __restrict__ Btl,
    const float* __restrict__ bias, float* __restrict__ C,
    float* __restrict__ Cpart, int M, int N, int K) {
  int t = threadIdx.x;
  int lane = t & 63, wave = t >> 6;
  int wr = wave >> 1, wc = wave & 1;
  int i0 = blockIdx.y * 64 + wr * 32;
  int j0 = blockIdx.x * 64 + wc * 32;
  int KS = gridDim.z;
  int kper = K / KS;
  size_t kbeg = (size_t)blockIdx.z * kper;
  int lr = lane & 15, lk = (lane >> 4) << 3;

  const u16* a0h = Ah  + (size_t)(i0 + lr) * K + kbeg + lk;
  const u16* a1h = a0h + (size_t)16 * K;
  const u16* a0l = Al  + (size_t)(i0 + lr) * K + kbeg + lk;
  const u16* a1l = a0l + (size_t)16 * K;
  const u16* b0h = Bth + (size_t)(j0 + lr) * K + kbeg + lk;
  const u16* b1h = b0h + (size_t)16 * K;
  const u16* b0l = Btl + (size_t)(j0 + lr) * K + kbeg + lk;
  const u16* b1l = b0l + (size_t)16 * K;

  f32x4 c00 = {0.f,0.f,0.f,0.f}, c01 = c00, c10 = c00, c11 = c00;
  for (int k = 0; k < kper; k += 32) {
    bf16x8 A0h = *(const bf16x8*)(a0h + k);
    bf16x8 A1h = *(const bf16x8*)(a1h + k);
    bf16x8 B0h = *(const bf16x8*)(b0h + k);
    bf16x8 B1h = *(const bf16x8*)(b1h + k);
    bf16x8 A0l = *(const bf16x8*)(a0l + k);
    bf16x8 A1l = *(const bf16x8*)(a1l + k);
    bf16x8 B0l = *(const bf16x8*)(b0l + k);
    bf16x8 B1l = *(const bf16x8*)(b1l + k);
    c00 = __builtin_amdgcn_mfma_f32_16x16x32_bf16(A0h, B0h, c00, 0, 0, 0);
    c01 = __builtin_amdgcn_mfma_f32_16x16x32_bf16(A0h, B1h, c01, 0, 0, 0);
    c10 = __builtin_amdgcn_mfma_f32_16x16x32_bf16(A1h, B0h, c10, 0, 0, 0);
    c11 = __builtin_amdgcn_mfma_f32_16x16x32_bf16(A1h, B1h, c11, 0, 0, 0);
    c00 = __builtin_amdgcn_mfma_f32_16x16x32_bf16(A0h, B0l, c00, 0, 0, 0);
    c01 = __builtin_amdgcn_mfma_f32_16x16x32_bf16(A0h, B1l, c01, 0, 0, 0);
    c10 = __builtin_amdgcn_mfma_f32_16x16x32_bf16(A1h, B0l, c10, 0, 0, 0);
    c11 = __builtin_amdgcn_mfma_f32_16x16x32_bf16(A1h, B1l, c11, 0, 0, 0);
    c00 = __builtin_amdgcn_mfma_f32_16x16x32_bf16(A0l, B0h, c00, 0, 0, 0);
    c01 = __builtin_amdgcn_mfma_f32_16x16x32_bf16(A0l, B1h, c01, 0, 0, 0);
    c10 = __builtin_amdgcn_mfma_f32_16x16x32_bf16(A1l, B0h, c10, 0, 0, 0);
    c11 = __builtin_amdgcn_mfma_f32_16x16x32_bf16(A1l, B1h, c11, 0, 0, 0);
  }

  int orow = (lane >> 4) << 2;
  int col0 = j0 + lr, col1 = j0 + 16 + lr;
  if (KS == 1) {
    float bb0 = bias[col0], bb1 = bias[col1];
    #pragma unroll
    for (int r = 0; r < 4; r++) {
      int row0 = i0 + orow + r, row1 = row0 + 16;
      C[(size_t)row0*N + col0] = c00[r] + bb0;
      C[(size_t)row0*N + col1] = c01[r] + bb1;
      C[(size_t)row1*N + col0] = c10[r] + bb0;
      C[(size_t)row1*N + col1] = c11[r] + bb1;
    }
  } else {
    float* dst = Cpart + (size_t)blockIdx.z * M * N;
    #pragma unroll
    for (int r = 0; r < 4; r++) {
      int row0 = i0 + orow + r, row1 = row0 + 16;
      dst[(size_t)row0*N + col0] = c00[r];
      dst[(size_t)row0*N + col1] = c01[r];
      dst[(size_t)row1*N + col0] = c10[r];
      dst[(size_t)row1*N + col1] = c11[r];
    }
  }
}

__global__ void k_reduce_bias(const float* __restrict__ part, const float* __restrict__ bias,
                              float* __restrict__ out, int MN, int N, int KS) {
  int e = blockIdx.x * 256 + threadIdx.x;
  if (e >= MN) return;
  float s = bias[e % N];
  for (int z = 0; z < KS; z++) s += part[(size_t)z*MN + e];
  out[e] = s;
}

// ---------------------------------------------------------------- fused feature-build + logits MFMA
__global__ __launch_bounds__(256) void k_feat_logits(
    const float* __restrict__ C1, const float* __restrict__ rot,
    const float* __restrict__ trans, const float* __restrict__ gamma,
    const float* __restrict__ w_c, const float* __restrict__ w_l,
    float* __restrict__ S) {
  __shared__ u16 Ash[64][72], Asl[64][72], Bsh[64][72], Bsl[64][72];  // 36.9 KB
  int h = blockIdx.z;
  int i0 = blockIdx.y * 64, j0 = blockIdx.x * 64;
  int t = threadIdx.x;

  if (t < 128) {
    int row = t & 63, side = t >> 6;      // side 0 = A (query), 1 = B (key)
    int gi = (side ? j0 : i0) + row;
    float R[9], tr[3];
    #pragma unroll
    for (int r = 0; r < 9; r++) R[r] = rot[(size_t)gi*9 + r];
    #pragma unroll
    for (int r = 0; r < 3; r++) tr[r] = trans[(size_t)gi*3 + r];
    float sc = w_c[0] * rsqrtf(32.f);
    float gp = gamma[h] * w_l[0];
    u16 (*Fh)[72] = side ? Bsh : Ash;
    u16 (*Fl)[72] = side ? Bsl : Asl;
    const float* qk = C1 + (size_t)gi*NPP + (side ? 384 : 0) + h*32;
    u16 h_, l_;
    #pragma unroll 8
    for (int d = 0; d < 32; d++) {
      float v = side ? qk[d] : sc*qk[d];
      split_bf16(v, h_, l_); Fh[row][d] = h_; Fl[row][d] = l_;
    }
    const float* pp = C1 + (size_t)gi*NPP + (side ? 1296 : 1152) + h*12;
    float ss = 0.f;
    #pragma unroll
    for (int p = 0; p < 4; p++) {
      float x = pp[p*3], y = pp[p*3+1], z = pp[p*3+2];
      #pragma unroll
      for (int r = 0; r < 3; r++) {
        float g = fmaf(R[r*3],x, fmaf(R[r*3+1],y, fmaf(R[r*3+2],z, tr[r])));
        float v = side ? g : gp*g;
        split_bf16(v, h_, l_); Fh[row][32+p*3+r] = h_; Fl[row][32+p*3+r] = l_;
        ss = fmaf(g,g,ss);
      }
    }
    float c44 = side ? 1.f : -0.5f*gp*ss;
    float c45 = side ? -0.5f*gp*ss : 1.f;
    split_bf16(c44, h_, l_); Fh[row][44] = h_; Fl[row][44] = l_;
    split_bf16(c45, h_, l_); Fh[row][45] = h_; Fl[row][45] = l_;
    #pragma unroll
    for (int d = 46; d < 64; d++) { Fh[row][d] = 0; Fl[row][d] = 0; }
  }
  __syncthreads();

  int lane = t & 63, wave = t >> 6, wr = wave >> 1, wc = wave & 1;
  int lr = lane & 15, lk = (lane >> 4) << 3;
  f32x4 c00 = {0.f,0.f,0.f,0.f}, c01 = c00, c10 = c00, c11 = c00;
  #pragma unroll
  for (int ks = 0; ks < 64; ks += 32) {
    bf16x8 A0h = *(const bf16x8*)&Ash[wr*32 + lr][ks + lk];
    bf16x8 A1h = *(const bf16x8*)&Ash[wr*32 + 16 + lr][ks + lk];
    bf16x8 B0h = *(const bf16x8*)&Bsh[wc*32 + lr][ks + lk];
    bf16x8 B1h = *(const bf16x8*)&Bsh[wc*32 + 16 + lr][ks + lk];
    bf16x8 A0l = *(const bf16x8*)&Asl[wr*32 + lr][ks + lk];
    bf16x8 A1l = *(const bf16x8*)&Asl[wr*32 + 16 + lr][ks + lk];
    bf16x8 B0l = *(const bf16x8*)&Bsl[wc*32 + lr][ks + lk];
    bf16x8 B1l = *(const bf16x8*)&Bsl[wc*32 + 16 + lr][ks + lk];
    c00 = __builtin_amdgcn_mfma_f32_16x16x32_bf16(A0h, B0h, c00, 0, 0, 0);
    c01 = __builtin_amdgcn_mfma_f32_16x16x32_bf16(A0h, B1h, c01, 0, 0, 0);
    c10 = __builtin_amdgcn_mfma_f32_16x16x32_bf16(A1h, B0h, c10, 0, 0, 0);
    c11 = __builtin_amdgcn_mfma_f32_16x16x32_bf16(A1h, B1h, c11, 0, 0, 0);
    c00 = __builtin_amdgcn_mfma_f32_16x16x32_bf16(A0h, B0l, c00, 0, 0, 0);
    c01 = __builtin_amdgcn_mfma_f32_16x16x32_bf16(A0h, B1l, c01, 0, 0, 0);
    c10 = __builtin_amdgcn_mfma_f32_16x16x32_bf16(A1h, B0l, c10, 0, 0, 0);
    c11 = __builtin_amdgcn_mfma_f32_16x16x32_bf16(A1h, B1l, c11, 0, 0, 0);
    c00 = __builtin_amdgcn_mfma_f32_16x16x32_bf16(A0l, B0h, c00, 0, 0, 0);
    c01 = __builtin_amdgcn_mfma_f32_16x16x32_bf16(A0l, B1h, c01, 0, 0, 0);
    c10 = __builtin_amdgcn_mfma_f32_16x16x32_bf16(A1l, B0h, c10, 0, 0, 0);
    c11 = __builtin_amdgcn_mfma_f32_16x16x32_bf16(A1l, B1h, c11, 0, 0, 0);
  }

  int orow = (lane >> 4) << 2;
  int col0 = j0 + wc*32 + lr, col1 = col0 + 16;
  int rbase = i0 + wr*32 + orow;
  #pragma unroll
  for (int r = 0; r < 4; r++) {
    S[((size_t)h*LQ + rbase + r)*LQ + col0]      = c00[r];
    S[((size_t)h*LQ + rbase + r)*LQ + col1]      = c01[r];
    S[((size_t)h*LQ + rbase + 16 + r)*LQ + col0] = c10[r];
    S[((size_t)h*LQ + rbase + 16 + r)*LQ + col1] = c11[r];
  }
}

// ---------------------------------------------------------------- Vt builder: [NH][64][LQ] split-bf16
// rows 0..31 = v, 32..55 = rotated vg, 56..63 = 0. i-contiguous writes = coalesced.
__global__ __launch_bounds__(256) void k_vt(
    const float* __restrict__ C1, const float* __restrict__ rot,
    const float* __restrict__ trans,
    u16* __restrict__ Vth, u16* __restrict__ Vtl) {
  int h = blockIdx.x;
  int i = blockIdx.y * 256 + threadIdx.x;
  float R[9], tr[3];
  #pragma unroll
  for (int r = 0; r < 9; r++) R[r] = rot[(size_t)i*9 + r];
  #pragma unroll
  for (int r = 0; r < 3; r++) tr[r] = trans[(size_t)i*3 + r];
  const float* vrow = C1 + (size_t)i*NPP + 768 + h*32;
  const float* prow = C1 + (size_t)i*NPP + 1440 + h*24;
  u16 h_, l_;
  #pragma unroll 8
  for (int n = 0; n < 32; n++) {
    split_bf16(vrow[n], h_, l_);
    Vth[((size_t)h*64 + n)*LQ + i] = h_;
    Vtl[((size_t)h*64 + n)*LQ + i] = l_;
  }
  #pragma unroll
  for (int p = 0; p < 8; p++) {
    float x = prow[p*3], y = prow[p*3+1], z = prow[p*3+2];
    #pragma unroll
    for (int r = 0; r < 3; r++) {
      float g = fmaf(R[r*3],x, fmaf(R[r*3+1],y, fmaf(R[r*3+2],z, tr[r])));
      split_bf16(g, h_, l_);
      Vth[((size_t)h*64 + 32 + p*3 + r)*LQ + i] = h_;
      Vtl[((size_t)h*64 + 32 + p*3 + r)*LQ + i] = l_;
    }
  }
  #pragma unroll
  for (int n = 56; n < 64; n++) {
    Vth[((size_t)h*64 + n)*LQ + i] = 0;
    Vtl[((size_t)h*64 + n)*LQ + i] = 0;
  }
}

// ---------------------------------------------------------------- pair chunk (r3 structure, measured 79us):
// one block per (i, j-chunk). bias GEMV + chunk softmax (S := e^{l-m_c}) +
// partial pair_out -> pairpart; msum[i][c][h] = {m_c, sum_c}.
__global__ __launch_bounds__(256, 2) void k_pair_chunk(
    const float* __restrict__ pair, const float* __restrict__ WpbT,
    const float* __restrict__ bpb, const float* __restrict__ mask,
    float* __restrict__ S, float* __restrict__ pairpart, float* __restrict__ msum) {
  __shared__ float tile[TJC*133];
  __shared__ float wt[NH*TJC];
  int i = blockIdx.x, c = blockIdx.y, t = threadIdx.x;
  int j0 = c*TJC;

  const float4* src = (const float4*)(pair + ((size_t)i*LQ + j0)*DPAIR);
  #pragma unroll
  for (int u = 0; u < 8; u++) {
    int e = t + u*256; int row = e >> 5, c4 = e & 31;
    *(float4*)&tile[row*133 + c4*4] = src[e];
  }

  int j = t & 63;
  int hg = __builtin_amdgcn_readfirstlane(t >> 6);
  int h0 = hg*3;
  float l[3];
  #pragma unroll
  for (int q = 0; q < 3; q++)
    l[q] = S[((size_t)(h0+q)*LQ + i)*LQ + j0 + j] + bpb[h0+q];
  bool dead = (mask[i] * mask[j0 + j] <= 0.f);
  __syncthreads();

  {
    const float* w0p = WpbT + (size_t)(h0+0)*DPAIR;
    const float* w1p = WpbT + (size_t)(h0+1)*DPAIR;
    const float* w2p = WpbT + (size_t)(h0+2)*DPAIR;
    float a0 = 0.f, a1 = 0.f, a2 = 0.f;
    #pragma unroll 8
    for (int k = 0; k < DPAIR; k += 4) {
      float4 pv = *(const float4*)&tile[j*133 + k];
      float4 w0 = *(const float4*)(w0p + k);
      float4 w1 = *(const float4*)(w1p + k);
      float4 w2 = *(const float4*)(w2p + k);
      a0 = fmaf(pv.x,w0.x, fmaf(pv.y,w0.y, fmaf(pv.z,w0.z, fmaf(pv.w,w0.w, a0))));
      a1 = fmaf(pv.x,w1.x, fmaf(pv.y,w1.y, fmaf(pv.z,w1.z, fmaf(pv.w,w1.w, a1))));
      a2 = fmaf(pv.x,w2.x, fmaf(pv.y,w2.y, fmaf(pv.z,w2.z, fmaf(pv.w,w2.w, a2))));
    }
    l[0] += a0; l[1] += a1; l[2] += a2;
    if (dead) { l[0] = -1e9f; l[1] = -1e9f; l[2] = -1e9f; }
  }

  #pragma unroll
  for (int q = 0; q < 3; q++) {
    float m = l[q];
    #pragma unroll
    for (int o = 32; o > 0; o >>= 1) m = fmaxf(m, __shfl_xor(m, o, 64));
    float w = __expf(l[q] - m);
    float sm = w;
    #pragma unroll
    for (int o = 32; o > 0; o >>= 1) sm += __shfl_xor(sm, o, 64);
    wt[(h0+q)*TJC + j] = w;
    S[((size_t)(h0+q)*LQ + i)*LQ + j0 + j] = w;
    if (j == 0) {
      float* dst = msum + (((size_t)i*NC + c)*NH + h0 + q)*2;
      dst[0] = m; dst[1] = sm;
    }
  }
  __syncthreads();

  int dg = t & 31, strip = t >> 5, jb = strip*8;
  float4 pv[8];
  #pragma unroll
  for (int q = 0; q < 8; q++) pv[q] = *(const float4*)&tile[(jb+q)*133 + dg*4];
  float4 acc[NH];
  #pragma unroll
  for (int h = 0; h < NH; h++) acc[h] = make_float4(0.f,0.f,0.f,0.f);
  #pragma unroll
  for (int h = 0; h < NH; h++) {
    float4 w0 = *(const float4*)&wt[h*TJC + jb];
    float4 w1 = *(const float4*)&wt[h*TJC + jb + 4];
    float wq[8] = {w0.x,w0.y,w0.z,w0.w,w1.x,w1.y,w1.z,w1.w};
    float4 a = acc[h];
    #pragma unroll
    for (int q = 0; q < 8; q++) {
      a.x = fmaf(wq[q], pv[q].x, a.x);
      a.y = fmaf(wq[q], pv[q].y, a.y);
      a.z = fmaf(wq[q], pv[q].z, a.z);
      a.w = fmaf(wq[q], pv[q].w, a.w);
    }
    acc[h] = a;
  }
  __syncthreads();

  float4* red4 = (float4*)tile;
  float4 tot[2];
  tot[0] = make_float4(0.f,0.f,0.f,0.f);
  tot[1] = make_float4(0.f,0.f,0.f,0.f);
  #pragma unroll
  for (int half = 0; half < 2; half++) {
    if ((strip >> 2) == half) {
      #pragma unroll
      for (int h = 0; h < NH; h++)
        red4[(((strip & 3)*NH) + h)*32 + dg] = acc[h];
    }
    __syncthreads();
    for (int e = t, u = 0; e < NH*32; e += 256, u++) {
      int rh = e >> 5, rd = e & 31;
      #pragma unroll
      for (int s4 = 0; s4 < 4; s4++) {
        float4 v = red4[((s4*NH) + rh)*32 + rd];
        tot[u].x += v.x; tot[u].y += v.y; tot[u].z += v.z; tot[u].w += v.w;
      }
    }
    __syncthreads();
  }
  for (int e = t, u = 0; e < NH*32; e += 256, u++) {
    int rh = e >> 5, rd = e & 31;
    *(float4*)&pairpart[(((size_t)i*NC + c)*NH + rh)*DPAIR + rd*4] = tot[u];
  }
}

// ---------------------------------------------------------------- scs + pair_out combine -> comb (split-bf16)
__global__ __launch_bounds__(384) void k_scs_pairout(
    const float* __restrict__ msum, const float* __restrict__ pairpart,
    float* __restrict__ scs_g,
    u16* __restrict__ combh, u16* __restrict__ combl) {
  __shared__ float scs[NH*NC];
  int i = blockIdx.x, t = threadIdx.x;
  if (t < NH) {
    float m = -3.0e38f;
    float mc[NC], sc_[NC];
    #pragma unroll
    for (int c = 0; c < NC; c++) {
      const float* p = msum + (((size_t)i*NC + c)*NH + t)*2;
      mc[c] = p[0]; sc_[c] = p[1];
      m = fmaxf(m, mc[c]);
    }
    float s = 0.f;
    #pragma unroll
    for (int c = 0; c < NC; c++) s += sc_[c] * __expf(mc[c] - m);
    float inv = 1.f / s;
    #pragma unroll
    for (int c = 0; c < NC; c++) {
      float v = __expf(mc[c] - m) * inv;
      scs[t*NC + c] = v;
      scs_g[((size_t)i*NH + t)*NC + c] = v;
    }
  }
  __syncthreads();
  int h = t >> 5, d = t & 31;
  float4 tot = make_float4(0.f,0.f,0.f,0.f);
  #pragma unroll
  for (int c = 0; c < NC; c++) {
    float sc = scs[h*NC + c];
    float4 v = *(const float4*)&pairpart[(((size_t)i*NC + c)*NH + h)*DPAIR + d*4];
    tot.x = fmaf(v.x, sc, tot.x); tot.y = fmaf(v.y, sc, tot.y);
    tot.z = fmaf(v.z, sc, tot.z); tot.w = fmaf(v.w, sc, tot.w);
  }
  size_t dst = (size_t)i*2304 + 768 + h*DPAIR + d*4;
  u16 h_, l_;
  split_bf16(tot.x, h_, l_); combh[dst+0] = h_; combl[dst+0] = l_;
  split_bf16(tot.y, h_, l_); combh[dst+1] = h_; combl[dst+1] = l_;
  split_bf16(tot.z, h_, l_); combh[dst+2] = h_; combl[dst+2] = l_;
  split_bf16(tot.w, h_, l_); combh[dst+3] = h_; combl[dst+3] = l_;
}

// ---------------------------------------------------------------- attn @ [v|vg] via MFMA, split-K=4 -> psum
// A-fragments built on the fly from S (f32, unnormalized) x scs_g -> split bf16.
// B-fragments direct from Vt. No LDS.
__global__ __launch_bounds__(256) void k_attn_mfma(
    const float* __restrict__ S, const float* __restrict__ scs_g,
    const u16* __restrict__ Vth, const u16* __restrict__ Vtl,
    float* __restrict__ psum) {
  int t = threadIdx.x;
  int lane = t & 63, wave = t >> 6;
  int wr = wave >> 1, wc = wave & 1;
  int z = blockIdx.x;                 // split-K
  int i0 = blockIdx.y * 64 + wr * 32;
  int h = blockIdx.z;
  int n0 = wc * 32;
  int lr = lane & 15, lk = (lane >> 4) << 3;

  const float* a0p = S + ((size_t)h*LQ + i0 + lr)*LQ + z*128 + lk;
  const float* a1p = a0p + (size_t)16*LQ;
  const float* s0p = scs_g + ((size_t)(i0 + lr)*NH + h)*NC + z*2;
  const float* s1p = scs_g + ((size_t)(i0 + 16 + lr)*NH + h)*NC + z*2;
  const u16* b0h = Vth + ((size_t)h*64 + n0 + lr)*LQ + z*128 + lk;
  const u16* b1h = b0h + (size_t)16*LQ;
  const u16* b0l = Vtl + ((size_t)h*64 + n0 + lr)*LQ + z*128 + lk;
  const u16* b1l = b0l + (size_t)16*LQ;

  f32x4 c00 = {0.f,0.f,0.f,0.f}, c01 = c00, c10 = c00, c11 = c00;
  #pragma unroll
  for (int k = 0; k < 128; k += 32) {
    int cc = (k >= 64) ? 1 : 0;
    float sc0 = s0p[cc], sc1 = s1p[cc];
    float4 av00 = *(const float4*)(a0p + k);
    float4 av01 = *(const float4*)(a0p + k + 4);
    float4 av10 = *(const float4*)(a1p + k);
    float4 av11 = *(const float4*)(a1p + k + 4);
    float a0v[8] = {av00.x,av00.y,av00.z,av00.w,av01.x,av01.y,av01.z,av01.w};
    float a1v[8] = {av10.x,av10.y,av10.z,av10.w,av11.x,av11.y,av11.z,av11.w};
    bf16x8 A0h = {}, A0l = {}, A1h = {}, A1l = {};
    #pragma unroll
    for (int e = 0; e < 8; e++) {
      u16 hh, ll;
      split_bf16(a0v[e]*sc0, hh, ll);
      A0h[e] = (short)hh; A0l[e] = (short)ll;
      split_bf16(a1v[e]*sc1, hh, ll);
      A1h[e] = (short)hh; A1l[e] = (short)ll;
    }
    bf16x8 B0h = *(const bf16x8*)(b0h + k);
    bf16x8 B1h = *(const bf16x8*)(b1h + k);
    bf16x8 B0l = *(const bf16x8*)(b0l + k);
    bf16x8 B1l = *(const bf16x8*)(b1l + k);
    c00 = __builtin_amdgcn_mfma_f32_16x16x32_bf16(A0h, B0h, c00, 0, 0, 0);
    c01 = __builtin_amdgcn_mfma_f32_16x16x32_bf16(A0h, B1h, c01, 0, 0, 0);
    c10 = __builtin_amdgcn_mfma_f32_16x16x32_bf16(A1h, B0h, c10, 0, 0, 0);
    c11 = __builtin_amdgcn_mfma_f32_16x16x32_bf16(A1h, B1h, c11, 0, 0, 0);
    c00 = __builtin_amdgcn_mfma_f32_16x16x32_bf16(A0h, B0l, c00, 0, 0, 0);
    c01 = __builtin_amdgcn_mfma_f32_16x16x32_bf16(A0h, B1l, c01, 0, 0, 0);
    c10 = __builtin_amdgcn_mfma_f32_16x16x32_bf16(A1h, B0l, c10, 0, 0, 0);
    c11 = __builtin_amdgcn_mfma_f32_16x16x32_bf16(A1h, B1l, c11, 0, 0, 0);
    c00 = __builtin_amdgcn_mfma_f32_16x16x32_bf16(A0l, B0h, c00, 0, 0, 0);
    c01 = __builtin_amdgcn_mfma_f32_16x16x32_bf16(A0l, B1h, c01, 0, 0, 0);
    c10 = __builtin_amdgcn_mfma_f32_16x16x32_bf16(A1l, B0h, c10, 0, 0, 0);
    c11 = __builtin_amdgcn_mfma_f32_16x16x32_bf16(A1l, B1h, c11, 0, 0, 0);
  }

  int orow = (lane >> 4) << 2;
  int col0 = n0 + lr, col1 = n0 + 16 + lr;
  #pragma unroll
  for (int r = 0; r < 4; r++) {
    int row0 = i0 + orow + r, row1 = row0 + 16;
    psum[(((size_t)z*LQ + row0)*NH + h)*64 + col0] = c00[r];
    psum[(((size_t)z*LQ + row0)*NH + h)*64 + col1] = c01[r];
    psum[(((size_t)z*LQ + row1)*NH + h)*64 + col0] = c10[r];
    psum[(((size_t)z*LQ + row1)*NH + h)*64 + col1] = c11[r];
  }
}

// ---------------------------------------------------------------- fused av_reduce + pts_feat -> comb (split-bf16)
__global__ void k_avpts(const float* __restrict__ psum, const float* __restrict__ rot,
                        const float* __restrict__ trans,
                        u16* __restrict__ combh, u16* __restrict__ combl) {
  int idx = blockIdx.x * 256 + threadIdx.x;
  if (idx >= LQ*NH*40) return;
  int w = idx % 40; int ih = idx / 40; int h = ih % NH; int i = ih / NH;
  size_t base = ((size_t)i*NH + h)*64;
  u16 h_, l_;
  if (w < 32) {
    float s = 0.f;
    for (int z = 0; z < 4; z++) s += psum[(size_t)z*LQ*NH*64 + base + w];
    split_bf16(s, h_, l_);
    combh[(size_t)i*2304 + h*32 + w] = h_;
    combl[(size_t)i*2304 + h*32 + w] = l_;
  } else {
    int p = w - 32;
    float g[3];
    #pragma unroll
    for (int r = 0; r < 3; r++) {
      int n = 32 + p*3 + r;
      float s = 0.f;
      for (int z = 0; z < 4; z++) s += psum[(size_t)z*LQ*NH*64 + base + n];
      g[r] = s;
    }
    const float* R = rot + (size_t)i*9;
    const float* tr = trans + (size_t)i*3;
    float x = g[0]-tr[0], y = g[1]-tr[1], z = g[2]-tr[2];
    float lx = fmaf(R[0],x, fmaf(R[3],y, R[6]*z));
    float ly = fmaf(R[1],x, fmaf(R[4],y, R[7]*z));
    float lz = fmaf(R[2],x, fmaf(R[5],y, R[8]*z));
    float nrm = sqrtf(fmaf(lx,lx, fmaf(ly,ly, lz*lz)));
    size_t dst = (size_t)i*2304 + 384 + (h*8 + p)*4;
    split_bf16(nrm, h_, l_); combh[dst+0] = h_; combl[dst+0] = l_;
    split_bf16(lx,  h_, l_); combh[dst+1] = h_; combl[dst+1] = l_;
    split_bf16(ly,  h_, l_); combh[dst+2] = h_; combl[dst+2] = l_;
    split_bf16(lz,  h_, l_); combh[dst+3] = h_; combl[dst+3] = l_;
  }
}

// ================================================================ launcher
extern "C" void kernel_launch(void* const* d_in, const int* in_sizes, int n_in,
                              void* d_out, int out_size, void* d_ws, size_t ws_size,
                              hipStream_t stream) {
  const float* single = (const float*)d_in[0];
  const float* pair   = (const float*)d_in[1];
  const float* rot    = (const float*)d_in[2];
  const float* trans  = (const float*)d_in[3];
  const float* mask   = (const float*)d_in[4];
  const float* ln_w   = (const float*)d_in[5];
  const float* ln_b   = (const float*)d_in[6];
  const float* Wq     = (const float*)d_in[7];
  const float* bq     = (const float*)d_in[8];
  const float* Wk     = (const float*)d_in[9];
  const float* bk     = (const float*)d_in[10];
  const float* Wv     = (const float*)d_in[11];
  const float* bv     = (const float*)d_in[12];
  const float* Wqp    = (const float*)d_in[13];
  const float* bqp    = (const float*)d_in[14];
  const float* Wkp    = (const float*)d_in[15];
  const float* bkp    = (const float*)d_in[16];
  const float* Wvp    = (const float*)d_in[17];
  const float* bvp    = (const float*)d_in[18];
  const float* Wpb    = (const float*)d_in[19];
  const float* bpb    = (const float*)d_in[20];
  const float* Wo     = (const float*)d_in[21];
  const float* bo     = (const float*)d_in[22];
  const float* w_c    = (const float*)d_in[23];
  const float* w_l    = (const float*)d_in[24];
  const float* gamma  = (const float*)d_in[25];
  float* out = (float*)d_out;

  float* p = (float*)d_ws;
  auto alloc = [&](size_t n) { float* r = p; p += n; return r; };
  u16* WcatTh = (u16*)alloc((size_t)NPP*DS/2);
  u16* WcatTl = (u16*)alloc((size_t)NPP*DS/2);
  u16* snh    = (u16*)alloc((size_t)LQ*DS/2);
  u16* snl    = (u16*)alloc((size_t)LQ*DS/2);
  u16* WoTh   = (u16*)alloc((size_t)DS*2304/2);
  u16* WoTl   = (u16*)alloc((size_t)DS*2304/2);
  u16* combh  = (u16*)alloc((size_t)LQ*2304/2);
  u16* combl  = (u16*)alloc((size_t)LQ*2304/2);
  u16* Vth    = (u16*)alloc((size_t)NH*64*LQ/2);
  u16* Vtl    = (u16*)alloc((size_t)NH*64*LQ/2);
  float* bcat    = alloc(NPP);
  float* WpbT    = alloc((size_t)NH*DPAIR);
  float* C1      = alloc((size_t)LQ*NPP);
  float* S       = alloc((size_t)NH*LQ*LQ);
  float* pairpart= alloc((size_t)LQ*NC*NH*DPAIR);
  float* msum    = alloc((size_t)LQ*NC*NH*2);
  float* scs_g   = alloc((size_t)LQ*NH*NC);
  float* psum    = alloc((size_t)4*LQ*NH*64);
  float* outpart = alloc((size_t)8*LQ*DS);

  k_prep<<<dim3(897), 256, 0, stream>>>(
      Wq, Wk, Wv, Wqp, Wkp, Wvp, bq, bk, bv, bqp, bkp, bvp, Wpb, Wo,
      single, ln_w, ln_b, WcatTh, WcatTl, bcat, WpbT, WoTh, WoTl, snh, snl);
  k_gemm_mfma<<<dim3(NPP/64, LQ/64, 1), 256, 0, stream>>>(
      snh, snl, WcatTh, WcatTl, bcat, C1, nullptr, LQ, NPP, DS);
  k_feat_logits<<<dim3(LQ/64, LQ/64, NH), 256, 0, stream>>>(
      C1, rot, trans, gamma, w_c, w_l, S);
  k_vt<<<dim3(NH, LQ/256), 256, 0, stream>>>(C1, rot, trans, Vth, Vtl);
  k_pair_chunk<<<dim3(LQ, NC), 256, 0, stream>>>(
      pair, WpbT, bpb, mask, S, pairpart, msum);
  k_scs_pairout<<<dim3(LQ), 384, 0, stream>>>(
      msum, pairpart, scs_g, combh, combl);
  k_attn_mfma<<<dim3(4, LQ/64, NH), 256, 0, stream>>>(
      S, scs_g, Vth, Vtl, psum);
  k_avpts<<<dim3((LQ*NH*40 + 255)/256), 256, 0, stream>>>(
      psum, rot, trans, combh, combl);
  k_gemm_mfma<<<dim3(DS/64, LQ/64, 8), 256, 0, stream>>>(
      combh, combl, WoTh, WoTl, nullptr, nullptr, outpart, LQ, DS, 2304);
  k_reduce_bias<<<dim3((LQ*DS + 255)/256), 256, 0, stream>>>(outpart, bo, out, LQ*DS, DS, 8);
}

// Round 8
// 345.291 us; speedup vs baseline: 1.2192x; 1.0055x over previous
//
#include <hip/hip_runtime.h>
#include <math.h>

// Problem constants
#define LQ    512
#define DS    384
#define DPAIR 128
#define NH    12
#define NPP   1792   // padded projection width
#define TJC   64     // j-chunk for pair kernel
#define NC    8      // number of j-chunks (LQ/TJC)
#define TSTR  140    // bf16 tile stride in u16 (280 B: 8B-aligned, 4-access/bank floor)

typedef unsigned short u16;
typedef unsigned int   u32;
typedef __attribute__((ext_vector_type(8))) short bf16x8;  // 8 bf16 in 4 VGPRs
typedef __attribute__((ext_vector_type(4))) float f32x4;

// round-to-nearest-even f32 -> bf16 bits
__device__ inline u16 bf16_rne(float x) {
  u32 u = __float_as_uint(x);
  u32 r = (u + 0x7FFFu + ((u >> 16) & 1u)) >> 16;
  return (u16)r;
}
// split x ~= hi + lo (both bf16); residual ~2^-17 relative
__device__ inline void split_bf16(float x, u16& h, u16& l) {
  u16 hb = bf16_rne(x);
  float hf = __uint_as_float(((u32)hb) << 16);
  h = hb;
  l = bf16_rne(x - hf);
}
__device__ inline float bf16_to_f32(u16 b) {
  return __uint_as_float(((u32)b) << 16);
}

// ---------------------------------------------------------------- fused prep:
// blocks 0..167   : Wcat transpose+split tiles -> WcatT [NPP][DS] bf16 hi/lo
// block  168      : bcat + WpbT
// blocks 169..384 : Wo transpose+split tiles   -> WoT [384][2304] bf16 hi/lo
// blocks 385..896 : layernorm rows -> sn split-bf16
__global__ __launch_bounds__(256) void k_prep(
    const float* __restrict__ Wq, const float* __restrict__ Wk,
    const float* __restrict__ Wv, const float* __restrict__ Wqp,
    const float* __restrict__ Wkp, const float* __restrict__ Wvp,
    const float* __restrict__ bq, const float* __restrict__ bk,
    const float* __restrict__ bv, const float* __restrict__ bqp,
    const float* __restrict__ bkp, const float* __restrict__ bvp,
    const float* __restrict__ Wpb, const float* __restrict__ Wo,
    const float* __restrict__ xs, const float* __restrict__ ln_w,
    const float* __restrict__ ln_b,
    u16* __restrict__ Wth, u16* __restrict__ Wtl,
    float* __restrict__ bcat, float* __restrict__ WpbT,
    u16* __restrict__ WoTh, u16* __restrict__ WoTl,
    u16* __restrict__ snh, u16* __restrict__ snl) {
  __shared__ u16 sh_hi[64][66], sh_lo[64][66];   // stride 66 -> conflict-free
  int blk = blockIdx.x, t = threadIdx.x;
  if (blk < 168) {
    int kb = blk / 28, cb = blk % 28;
    int k0 = kb * 64, c0 = cb * 64;
    for (int e = t; e < 4096; e += 256) {
      int rr = e >> 6, cc = e & 63;
      int k = k0 + rr, c = c0 + cc;
      float v = 0.f;
      if (c < 384)       v = Wq[k*384 + c];
      else if (c < 768)  v = Wk[k*384 + c-384];
      else if (c < 1152) v = Wv[k*384 + c-768];
      else if (c < 1296) v = Wqp[k*144 + c-1152];
      else if (c < 1440) v = Wkp[k*144 + c-1296];
      else if (c < 1728) v = Wvp[k*288 + c-1440];
      u16 h_, l_; split_bf16(v, h_, l_);
      sh_hi[rr][cc] = h_; sh_lo[rr][cc] = l_;
    }
    __syncthreads();
    for (int e = t; e < 4096; e += 256) {
      int cc = e >> 6, kk = e & 63;
      Wth[(size_t)(c0+cc)*DS + k0 + kk] = sh_hi[kk][cc];
      Wtl[(size_t)(c0+cc)*DS + k0 + kk] = sh_lo[kk][cc];
    }
  } else if (blk == 168) {
    for (int e = t; e < NPP + NH*DPAIR; e += 256) {
      if (e < NPP) {
        int c = e;
        float v = 0.f;
        if (c < 384)       v = bq[c];
        else if (c < 768)  v = bk[c-384];
        else if (c < 1152) v = bv[c-768];
        else if (c < 1296) v = bqp[c-1152];
        else if (c < 1440) v = bkp[c-1296];
        else if (c < 1728) v = bvp[c-1440];
        bcat[c] = v;
      } else {
        int e2 = e - NPP;
        int k = e2 / NH, h = e2 % NH;
        WpbT[h*DPAIR + k] = Wpb[e2];
      }
    }
  } else if (blk < 385) {
    int idx = blk - 169;
    int kt = idx % 36, nt = idx / 36;      // Wo is [2304][384]
    int k0 = kt * 64, n0 = nt * 64;
    for (int e = t; e < 4096; e += 256) {
      int rr = e >> 6, cc = e & 63;
      float v = Wo[(size_t)(k0+rr)*384 + n0 + cc];
      u16 h_, l_; split_bf16(v, h_, l_);
      sh_hi[rr][cc] = h_; sh_lo[rr][cc] = l_;
    }
    __syncthreads();
    for (int e = t; e < 4096; e += 256) {
      int cc = e >> 6, kk = e & 63;
      WoTh[(size_t)(n0+cc)*2304 + k0 + kk] = sh_hi[kk][cc];
      WoTl[(size_t)(n0+cc)*2304 + k0 + kk] = sh_lo[kk][cc];
    }
  } else {
    // layernorm row, 256 threads covering 384 elements
    int i = blk - 385;
    float* red = (float*)&sh_hi[0][0];
    float a0 = xs[i*DS + t];
    float a1 = (t < 128) ? xs[i*DS + 256 + t] : 0.f;
    red[t] = a0 + a1; __syncthreads();
    for (int s = 128; s > 0; s >>= 1) { if (t < s) red[t] += red[t+s]; __syncthreads(); }
    float mu = red[0] * (1.f/384.f);
    __syncthreads();
    float d0 = a0 - mu, d1 = (t < 128) ? (a1 - mu) : 0.f;
    red[t] = d0*d0 + d1*d1; __syncthreads();
    for (int s = 128; s > 0; s >>= 1) { if (t < s) red[t] += red[t+s]; __syncthreads(); }
    float rstd = rsqrtf(red[0] * (1.f/384.f) + 1e-5f);
    u16 h_, l_;
    float y0 = d0*rstd*ln_w[t] + ln_b[t];
    split_bf16(y0, h_, l_); snh[i*DS + t] = h_; snl[i*DS + t] = l_;
    if (t < 128) {
      float y1 = d1*rstd*ln_w[256+t] + ln_b[256+t];
      split_bf16(y1, h_, l_); snh[i*DS + 256 + t] = h_; snl[i*DS + 256 + t] = l_;
    }
  }
}

// ---------------------------------------------------------------- MFMA GEMM: C[M][N] = A[M][K] @ Bt[N][K]^T
// 3-term compensated bf16 (AhBh + AhBl + AlBh), f32 accumulate -> ~f32 accuracy.
__global__ __launch_bounds__(256) void k_gemm_mfma(
    const u16* __restrict__ Ah, const u16* __restrict__ Al,
    const u16* __restrict__ Bth, const u16* __restrict__ Btl,
    const float* __restrict__ bias, float* __restrict__ C,
    float* __restrict__ Cpart, int M, int N, int K) {
  int t = threadIdx.x;
  int lane = t & 63, wave = t >> 6;
  int wr = wave >> 1, wc = wave & 1;
  int i0 = blockIdx.y * 64 + wr * 32;
  int j0 = blockIdx.x * 64 + wc * 32;
  int KS = gridDim.z;
  int kper = K / KS;
  size_t kbeg = (size_t)blockIdx.z * kper;
  int lr = lane & 15, lk = (lane >> 4) << 3;

  const u16* a0h = Ah  + (size_t)(i0 + lr) * K + kbeg + lk;
  const u16* a1h = a0h + (size_t)16 * K;
  const u16* a0l = Al  + (size_t)(i0 + lr) * K + kbeg + lk;
  const u16* a1l = a0l + (size_t)16 * K;
  const u16* b0h = Bth + (size_t)(j0 + lr) * K + kbeg + lk;
  const u16* b1h = b0h + (size_t)16 * K;
  const u16* b0l = Btl + (size_t)(j0 + lr) * K + kbeg + lk;
  const u16* b1l = b0l + (size_t)16 * K;

  f32x4 c00 = {0.f,0.f,0.f,0.f}, c01 = c00, c10 = c00, c11 = c00;
  for (int k = 0; k < kper; k += 32) {
    bf16x8 A0h = *(const bf16x8*)(a0h + k);
    bf16x8 A1h = *(const bf16x8*)(a1h + k);
    bf16x8 B0h = *(const bf16x8*)(b0h + k);
    bf16x8 B1h = *(const bf16x8*)(b1h + k);
    bf16x8 A0l = *(const bf16x8*)(a0l + k);
    bf16x8 A1l = *(const bf16x8*)(a1l + k);
    bf16x8 B0l = *(const bf16x8*)(b0l + k);
    bf16x8 B1l = *(const bf16x8*)(b1l + k);
    c00 = __builtin_amdgcn_mfma_f32_16x16x32_bf16(A0h, B0h, c00, 0, 0, 0);
    c01 = __builtin_amdgcn_mfma_f32_16x16x32_bf16(A0h, B1h, c01, 0, 0, 0);
    c10 = __builtin_amdgcn_mfma_f32_16x16x32_bf16(A1h, B0h, c10, 0, 0, 0);
    c11 = __builtin_amdgcn_mfma_f32_16x16x32_bf16(A1h, B1h, c11, 0, 0, 0);
    c00 = __builtin_amdgcn_mfma_f32_16x16x32_bf16(A0h, B0l, c00, 0, 0, 0);
    c01 = __builtin_amdgcn_mfma_f32_16x16x32_bf16(A0h, B1l, c01, 0, 0, 0);
    c10 = __builtin_amdgcn_mfma_f32_16x16x32_bf16(A1h, B0l, c10, 0, 0, 0);
    c11 = __builtin_amdgcn_mfma_f32_16x16x32_bf16(A1h, B1l, c11, 0, 0, 0);
    c00 = __builtin_amdgcn_mfma_f32_16x16x32_bf16(A0l, B0h, c00, 0, 0, 0);
    c01 = __builtin_amdgcn_mfma_f32_16x16x32_bf16(A0l, B1h, c01, 0, 0, 0);
    c10 = __builtin_amdgcn_mfma_f32_16x16x32_bf16(A1l, B0h, c10, 0, 0, 0);
    c11 = __builtin_amdgcn_mfma_f32_16x16x32_bf16(A1l, B1h, c11, 0, 0, 0);
  }

  int orow = (lane >> 4) << 2;
  int col0 = j0 + lr, col1 = j0 + 16 + lr;
  if (KS == 1) {
    float bb0 = bias[col0], bb1 = bias[col1];
    #pragma unroll
    for (int r = 0; r < 4; r++) {
      int row0 = i0 + orow + r, row1 = row0 + 16;
      C[(size_t)row0*N + col0] = c00[r] + bb0;
      C[(size_t)row0*N + col1] = c01[r] + bb1;
      C[(size_t)row1*N + col0] = c10[r] + bb0;
      C[(size_t)row1*N + col1] = c11[r] + bb1;
    }
  } else {
    float* dst = Cpart + (size_t)blockIdx.z * M * N;
    #pragma unroll
    for (int r = 0; r < 4; r++) {
      int row0 = i0 + orow + r, row1 = row0 + 16;
      dst[(size_t)row0*N + col0] = c00[r];
      dst[(size_t)row0*N + col1] = c01[r];
      dst[(size_t)row1*N + col0] = c10[r];
      dst[(size_t)row1*N + col1] = c11[r];
    }
  }
}

__global__ void k_reduce_bias(const float* __restrict__ part, const float* __restrict__ bias,
                              float* __restrict__ out, int MN, int N, int KS) {
  int e = blockIdx.x * 256 + threadIdx.x;
  if (e >= MN) return;
  float s = bias[e % N];
  for (int z = 0; z < KS; z++) s += part[(size_t)z*MN + e];
  out[e] = s;
}

// ---------------------------------------------------------------- fused feature-build + logits MFMA
__global__ __launch_bounds__(256) void k_feat_logits(
    const float* __restrict__ C1, const float* __restrict__ rot,
    const float* __restrict__ trans, const float* __restrict__ gamma,
    const float* __restrict__ w_c, const float* __restrict__ w_l,
    float* __restrict__ S) {
  __shared__ u16 Ash[64][72], Asl[64][72], Bsh[64][72], Bsl[64][72];  // 36.9 KB
  int h = blockIdx.z;
  int i0 = blockIdx.y * 64, j0 = blockIdx.x * 64;
  int t = threadIdx.x;

  if (t < 128) {
    int row = t & 63, side = t >> 6;      // side 0 = A (query), 1 = B (key)
    int gi = (side ? j0 : i0) + row;
    float R[9], tr[3];
    #pragma unroll
    for (int r = 0; r < 9; r++) R[r] = rot[(size_t)gi*9 + r];
    #pragma unroll
    for (int r = 0; r < 3; r++) tr[r] = trans[(size_t)gi*3 + r];
    float sc = w_c[0] * rsqrtf(32.f);
    float gp = gamma[h] * w_l[0];
    u16 (*Fh)[72] = side ? Bsh : Ash;
    u16 (*Fl)[72] = side ? Bsl : Asl;
    const float* qk = C1 + (size_t)gi*NPP + (side ? 384 : 0) + h*32;
    u16 h_, l_;
    #pragma unroll 8
    for (int d = 0; d < 32; d++) {
      float v = side ? qk[d] : sc*qk[d];
      split_bf16(v, h_, l_); Fh[row][d] = h_; Fl[row][d] = l_;
    }
    const float* pp = C1 + (size_t)gi*NPP + (side ? 1296 : 1152) + h*12;
    float ss = 0.f;
    #pragma unroll
    for (int p = 0; p < 4; p++) {
      float x = pp[p*3], y = pp[p*3+1], z = pp[p*3+2];
      #pragma unroll
      for (int r = 0; r < 3; r++) {
        float g = fmaf(R[r*3],x, fmaf(R[r*3+1],y, fmaf(R[r*3+2],z, tr[r])));
        float v = side ? g : gp*g;
        split_bf16(v, h_, l_); Fh[row][32+p*3+r] = h_; Fl[row][32+p*3+r] = l_;
        ss = fmaf(g,g,ss);
      }
    }
    float c44 = side ? 1.f : -0.5f*gp*ss;
    float c45 = side ? -0.5f*gp*ss : 1.f;
    split_bf16(c44, h_, l_); Fh[row][44] = h_; Fl[row][44] = l_;
    split_bf16(c45, h_, l_); Fh[row][45] = h_; Fl[row][45] = l_;
    #pragma unroll
    for (int d = 46; d < 64; d++) { Fh[row][d] = 0; Fl[row][d] = 0; }
  }
  __syncthreads();

  int lane = t & 63, wave = t >> 6, wr = wave >> 1, wc = wave & 1;
  int lr = lane & 15, lk = (lane >> 4) << 3;
  f32x4 c00 = {0.f,0.f,0.f,0.f}, c01 = c00, c10 = c00, c11 = c00;
  #pragma unroll
  for (int ks = 0; ks < 64; ks += 32) {
    bf16x8 A0h = *(const bf16x8*)&Ash[wr*32 + lr][ks + lk];
    bf16x8 A1h = *(const bf16x8*)&Ash[wr*32 + 16 + lr][ks + lk];
    bf16x8 B0h = *(const bf16x8*)&Bsh[wc*32 + lr][ks + lk];
    bf16x8 B1h = *(const bf16x8*)&Bsh[wc*32 + 16 + lr][ks + lk];
    bf16x8 A0l = *(const bf16x8*)&Asl[wr*32 + lr][ks + lk];
    bf16x8 A1l = *(const bf16x8*)&Asl[wr*32 + 16 + lr][ks + lk];
    bf16x8 B0l = *(const bf16x8*)&Bsl[wc*32 + lr][ks + lk];
    bf16x8 B1l = *(const bf16x8*)&Bsl[wc*32 + 16 + lr][ks + lk];
    c00 = __builtin_amdgcn_mfma_f32_16x16x32_bf16(A0h, B0h, c00, 0, 0, 0);
    c01 = __builtin_amdgcn_mfma_f32_16x16x32_bf16(A0h, B1h, c01, 0, 0, 0);
    c10 = __builtin_amdgcn_mfma_f32_16x16x32_bf16(A1h, B0h, c10, 0, 0, 0);
    c11 = __builtin_amdgcn_mfma_f32_16x16x32_bf16(A1h, B1h, c11, 0, 0, 0);
    c00 = __builtin_amdgcn_mfma_f32_16x16x32_bf16(A0h, B0l, c00, 0, 0, 0);
    c01 = __builtin_amdgcn_mfma_f32_16x16x32_bf16(A0h, B1l, c01, 0, 0, 0);
    c10 = __builtin_amdgcn_mfma_f32_16x16x32_bf16(A1h, B0l, c10, 0, 0, 0);
    c11 = __builtin_amdgcn_mfma_f32_16x16x32_bf16(A1h, B1l, c11, 0, 0, 0);
    c00 = __builtin_amdgcn_mfma_f32_16x16x32_bf16(A0l, B0h, c00, 0, 0, 0);
    c01 = __builtin_amdgcn_mfma_f32_16x16x32_bf16(A0l, B1h, c01, 0, 0, 0);
    c10 = __builtin_amdgcn_mfma_f32_16x16x32_bf16(A1l, B0h, c10, 0, 0, 0);
    c11 = __builtin_amdgcn_mfma_f32_16x16x32_bf16(A1l, B1h, c11, 0, 0, 0);
  }

  int orow = (lane >> 4) << 2;
  int col0 = j0 + wc*32 + lr, col1 = col0 + 16;
  int rbase = i0 + wr*32 + orow;
  #pragma unroll
  for (int r = 0; r < 4; r++) {
    S[((size_t)h*LQ + rbase + r)*LQ + col0]      = c00[r];
    S[((size_t)h*LQ + rbase + r)*LQ + col1]      = c01[r];
    S[((size_t)h*LQ + rbase + 16 + r)*LQ + col0] = c10[r];
    S[((size_t)h*LQ + rbase + 16 + r)*LQ + col1] = c11[r];
  }
}

// ---------------------------------------------------------------- Vt builder: [NH][64][LQ] split-bf16
__global__ __launch_bounds__(256) void k_vt(
    const float* __restrict__ C1, const float* __restrict__ rot,
    const float* __restrict__ trans,
    u16* __restrict__ Vth, u16* __restrict__ Vtl) {
  int h = blockIdx.x;
  int i = blockIdx.y * 256 + threadIdx.x;
  float R[9], tr[3];
  #pragma unroll
  for (int r = 0; r < 9; r++) R[r] = rot[(size_t)i*9 + r];
  #pragma unroll
  for (int r = 0; r < 3; r++) tr[r] = trans[(size_t)i*3 + r];
  const float* vrow = C1 + (size_t)i*NPP + 768 + h*32;
  const float* prow = C1 + (size_t)i*NPP + 1440 + h*24;
  u16 h_, l_;
  #pragma unroll 8
  for (int n = 0; n < 32; n++) {
    split_bf16(vrow[n], h_, l_);
    Vth[((size_t)h*64 + n)*LQ + i] = h_;
    Vtl[((size_t)h*64 + n)*LQ + i] = l_;
  }
  #pragma unroll
  for (int p = 0; p < 8; p++) {
    float x = prow[p*3], y = prow[p*3+1], z = prow[p*3+2];
    #pragma unroll
    for (int r = 0; r < 3; r++) {
      float g = fmaf(R[r*3],x, fmaf(R[r*3+1],y, fmaf(R[r*3+2],z, tr[r])));
      split_bf16(g, h_, l_);
      Vth[((size_t)h*64 + 32 + p*3 + r)*LQ + i] = h_;
      Vtl[((size_t)h*64 + 32 + p*3 + r)*LQ + i] = l_;
    }
  }
  #pragma unroll
  for (int n = 56; n < 64; n++) {
    Vth[((size_t)h*64 + n)*LQ + i] = 0;
    Vtl[((size_t)h*64 + n)*LQ + i] = 0;
  }
}

// ---------------------------------------------------------------- pair chunk, bf16 tile (occupancy 2x):
// one block per (i, j-chunk). Tile stored as bf16 [64][TSTR] (17.9 KB) unioned
// with the reduce scratch (24 KB) -> ~24.6 KB LDS, 6 blocks/CU vs 4.
__global__ __launch_bounds__(256, 4) void k_pair_chunk(
    const float* __restrict__ pair, const float* __restrict__ WpbT,
    const float* __restrict__ bpb, const float* __restrict__ mask,
    float* __restrict__ S, float* __restrict__ pairpart, float* __restrict__ msum) {
  __shared__ __align__(16) char lds_raw[24576];
  u16*   tile = (u16*)lds_raw;                      // [64][TSTR] bf16
  float* wt   = (float*)(lds_raw + 64*TSTR*2);      // [NH][TJC], 3 KB (17920..20992)
  float4* red4 = (float4*)lds_raw;                  // reduce scratch (aliases tile+wt)

  int i = blockIdx.x, c = blockIdx.y, t = threadIdx.x;
  int j0 = c*TJC;

  // stage 64x128 tile: f32 -> bf16 -> ushort4 (8B) stores
  const float4* src = (const float4*)(pair + ((size_t)i*LQ + j0)*DPAIR);
  #pragma unroll
  for (int u = 0; u < 8; u++) {
    int e = t + u*256; int row = e >> 5, c4 = e & 31;
    float4 v = src[e];
    ushort4 b;
    b.x = bf16_rne(v.x); b.y = bf16_rne(v.y);
    b.z = bf16_rne(v.z); b.w = bf16_rne(v.w);
    *(ushort4*)&tile[row*TSTR + c4*4] = b;
  }

  int j = t & 63;
  int hg = __builtin_amdgcn_readfirstlane(t >> 6);
  int h0 = hg*3;
  float l[3];
  #pragma unroll
  for (int q = 0; q < 3; q++)
    l[q] = S[((size_t)(h0+q)*LQ + i)*LQ + j0 + j] + bpb[h0+q];
  bool dead = (mask[i] * mask[j0 + j] <= 0.f);
  __syncthreads();

  // phase A: pair-bias GEMV from bf16 tile
  {
    const float* w0p = WpbT + (size_t)(h0+0)*DPAIR;
    const float* w1p = WpbT + (size_t)(h0+1)*DPAIR;
    const float* w2p = WpbT + (size_t)(h0+2)*DPAIR;
    float a0 = 0.f, a1 = 0.f, a2 = 0.f;
    #pragma unroll 8
    for (int k = 0; k < DPAIR; k += 4) {
      ushort4 pb = *(const ushort4*)&tile[j*TSTR + k];
      float px = bf16_to_f32(pb.x), py = bf16_to_f32(pb.y);
      float pz = bf16_to_f32(pb.z), pw = bf16_to_f32(pb.w);
      float4 w0 = *(const float4*)(w0p + k);
      float4 w1 = *(const float4*)(w1p + k);
      float4 w2 = *(const float4*)(w2p + k);
      a0 = fmaf(px,w0.x, fmaf(py,w0.y, fmaf(pz,w0.z, fmaf(pw,w0.w, a0))));
      a1 = fmaf(px,w1.x, fmaf(py,w1.y, fmaf(pz,w1.z, fmaf(pw,w1.w, a1))));
      a2 = fmaf(px,w2.x, fmaf(py,w2.y, fmaf(pz,w2.z, fmaf(pw,w2.w, a2))));
    }
    l[0] += a0; l[1] += a1; l[2] += a2;
    if (dead) { l[0] = -1e9f; l[1] = -1e9f; l[2] = -1e9f; }
  }

  // chunk softmax: per-wave shuffle reduce, 3 heads
  #pragma unroll
  for (int q = 0; q < 3; q++) {
    float m = l[q];
    #pragma unroll
    for (int o = 32; o > 0; o >>= 1) m = fmaxf(m, __shfl_xor(m, o, 64));
    float w = __expf(l[q] - m);
    float sm = w;
    #pragma unroll
    for (int o = 32; o > 0; o >>= 1) sm += __shfl_xor(sm, o, 64);
    wt[(h0+q)*TJC + j] = w;
    S[((size_t)(h0+q)*LQ + i)*LQ + j0 + j] = w;
    if (j == 0) {
      float* dst = msum + (((size_t)i*NC + c)*NH + h0 + q)*2;
      dst[0] = m; dst[1] = sm;
    }
  }
  __syncthreads();

  // phase C: partial pair_out from bf16 tile (amortized over 12 heads)
  int dg = t & 31, strip = t >> 5, jb = strip*8;
  float4 pv[8];
  #pragma unroll
  for (int q = 0; q < 8; q++) {
    ushort4 pb = *(const ushort4*)&tile[(jb+q)*TSTR + dg*4];
    pv[q].x = bf16_to_f32(pb.x); pv[q].y = bf16_to_f32(pb.y);
    pv[q].z = bf16_to_f32(pb.z); pv[q].w = bf16_to_f32(pb.w);
  }
  float4 acc[NH];
  #pragma unroll
  for (int h = 0; h < NH; h++) acc[h] = make_float4(0.f,0.f,0.f,0.f);
  #pragma unroll
  for (int h = 0; h < NH; h++) {
    float4 w0 = *(const float4*)&wt[h*TJC + jb];
    float4 w1 = *(const float4*)&wt[h*TJC + jb + 4];
    float wq[8] = {w0.x,w0.y,w0.z,w0.w,w1.x,w1.y,w1.z,w1.w};
    float4 a = acc[h];
    #pragma unroll
    for (int q = 0; q < 8; q++) {
      a.x = fmaf(wq[q], pv[q].x, a.x);
      a.y = fmaf(wq[q], pv[q].y, a.y);
      a.z = fmaf(wq[q], pv[q].z, a.z);
      a.w = fmaf(wq[q], pv[q].w, a.w);
    }
    acc[h] = a;
  }
  __syncthreads();   // tile + wt reads done; reuse as reduce scratch

  float4 tot[2];
  tot[0] = make_float4(0.f,0.f,0.f,0.f);
  tot[1] = make_float4(0.f,0.f,0.f,0.f);
  #pragma unroll
  for (int half = 0; half < 2; half++) {
    if ((strip >> 2) == half) {
      #pragma unroll
      for (int h = 0; h < NH; h++)
        red4[(((strip & 3)*NH) + h)*32 + dg] = acc[h];
    }
    __syncthreads();
    for (int e = t, u = 0; e < NH*32; e += 256, u++) {
      int rh = e >> 5, rd = e & 31;
      #pragma unroll
      for (int s4 = 0; s4 < 4; s4++) {
        float4 v = red4[((s4*NH) + rh)*32 + rd];
        tot[u].x += v.x; tot[u].y += v.y; tot[u].z += v.z; tot[u].w += v.w;
      }
    }
    __syncthreads();
  }
  for (int e = t, u = 0; e < NH*32; e += 256, u++) {
    int rh = e >> 5, rd = e & 31;
    *(float4*)&pairpart[(((size_t)i*NC + c)*NH + rh)*DPAIR + rd*4] = tot[u];
  }
}

// ---------------------------------------------------------------- scs + pair_out combine + normalized split-bf16 Aw
__global__ __launch_bounds__(384) void k_scs_pairout(
    const float* __restrict__ msum, const float* __restrict__ pairpart,
    const float* __restrict__ S,
    u16* __restrict__ Awh, u16* __restrict__ Awl,
    u16* __restrict__ combh, u16* __restrict__ combl) {
  __shared__ float scs[NH*NC];
  int i = blockIdx.x, t = threadIdx.x;
  if (t < NH) {
    float m = -3.0e38f;
    float mc[NC], sc_[NC];
    #pragma unroll
    for (int c = 0; c < NC; c++) {
      const float* p = msum + (((size_t)i*NC + c)*NH + t)*2;
      mc[c] = p[0]; sc_[c] = p[1];
      m = fmaxf(m, mc[c]);
    }
    float s = 0.f;
    #pragma unroll
    for (int c = 0; c < NC; c++) s += sc_[c] * __expf(mc[c] - m);
    float inv = 1.f / s;
    #pragma unroll
    for (int c = 0; c < NC; c++)
      scs[t*NC + c] = __expf(mc[c] - m) * inv;
  }
  __syncthreads();
  // pair_out combine -> comb cols 768..2304 (split-bf16)
  int h = t >> 5, d = t & 31;
  float4 tot = make_float4(0.f,0.f,0.f,0.f);
  #pragma unroll
  for (int c = 0; c < NC; c++) {
    float sc = scs[h*NC + c];
    float4 v = *(const float4*)&pairpart[(((size_t)i*NC + c)*NH + h)*DPAIR + d*4];
    tot.x = fmaf(v.x, sc, tot.x); tot.y = fmaf(v.y, sc, tot.y);
    tot.z = fmaf(v.z, sc, tot.z); tot.w = fmaf(v.w, sc, tot.w);
  }
  size_t cb = (size_t)i*2304 + 768 + h*DPAIR + d*4;
  u16 h_, l_;
  split_bf16(tot.x, h_, l_); combh[cb+0] = h_; combl[cb+0] = l_;
  split_bf16(tot.y, h_, l_); combh[cb+1] = h_; combl[cb+1] = l_;
  split_bf16(tot.z, h_, l_); combh[cb+2] = h_; combl[cb+2] = l_;
  split_bf16(tot.w, h_, l_); combh[cb+3] = h_; combl[cb+3] = l_;
  // normalized attention weights -> split-bf16 Aw[h][i][j]
  for (int e = t; e < NH*LQ; e += 384) {
    int hh2 = e >> 9, j = e & 511;
    float w = S[((size_t)hh2*LQ + i)*LQ + j] * scs[hh2*NC + (j >> 6)];
    split_bf16(w, h_, l_);
    Awh[((size_t)hh2*LQ + i)*LQ + j] = h_;
    Awl[((size_t)hh2*LQ + i)*LQ + j] = l_;
  }
}

// ---------------------------------------------------------------- attn @ [v|vg] via MFMA, split-K=4 -> psum
// pure loads (Aw pre-split) + 12 MFMA per k-step. No LDS, no VALU splitting.
__global__ __launch_bounds__(256) void k_attn_mfma(
    const u16* __restrict__ Awh, const u16* __restrict__ Awl,
    const u16* __restrict__ Vth, const u16* __restrict__ Vtl,
    float* __restrict__ psum) {
  int t = threadIdx.x;
  int lane = t & 63, wave = t >> 6;
  int wr = wave >> 1, wc = wave & 1;
  int z = blockIdx.x;                 // split-K
  int i0 = blockIdx.y * 64 + wr * 32;
  int h = blockIdx.z;
  int n0 = wc * 32;
  int lr = lane & 15, lk = (lane >> 4) << 3;
  size_t kb = (size_t)z*128 + lk;

  const u16* a0h = Awh + ((size_t)h*LQ + i0 + lr)*LQ + kb;
  const u16* a1h = a0h + (size_t)16*LQ;
  const u16* a0l = Awl + ((size_t)h*LQ + i0 + lr)*LQ + kb;
  const u16* a1l = a0l + (size_t)16*LQ;
  const u16* b0h = Vth + ((size_t)h*64 + n0 + lr)*LQ + kb;
  const u16* b1h = b0h + (size_t)16*LQ;
  const u16* b0l = Vtl + ((size_t)h*64 + n0 + lr)*LQ + kb;
  const u16* b1l = b0l + (size_t)16*LQ;

  f32x4 c00 = {0.f,0.f,0.f,0.f}, c01 = c00, c10 = c00, c11 = c00;
  #pragma unroll
  for (int k = 0; k < 128; k += 32) {
    bf16x8 A0h = *(const bf16x8*)(a0h + k);
    bf16x8 A1h = *(const bf16x8*)(a1h + k);
    bf16x8 B0h = *(const bf16x8*)(b0h + k);
    bf16x8 B1h = *(const bf16x8*)(b1h + k);
    bf16x8 A0l = *(const bf16x8*)(a0l + k);
    bf16x8 A1l = *(const bf16x8*)(a1l + k);
    bf16x8 B0l = *(const bf16x8*)(b0l + k);
    bf16x8 B1l = *(const bf16x8*)(b1l + k);
    c00 = __builtin_amdgcn_mfma_f32_16x16x32_bf16(A0h, B0h, c00, 0, 0, 0);
    c01 = __builtin_amdgcn_mfma_f32_16x16x32_bf16(A0h, B1h, c01, 0, 0, 0);
    c10 = __builtin_amdgcn_mfma_f32_16x16x32_bf16(A1h, B0h, c10, 0, 0, 0);
    c11 = __builtin_amdgcn_mfma_f32_16x16x32_bf16(A1h, B1h, c11, 0, 0, 0);
    c00 = __builtin_amdgcn_mfma_f32_16x16x32_bf16(A0h, B0l, c00, 0, 0, 0);
    c01 = __builtin_amdgcn_mfma_f32_16x16x32_bf16(A0h, B1l, c01, 0, 0, 0);
    c10 = __builtin_amdgcn_mfma_f32_16x16x32_bf16(A1h, B0l, c10, 0, 0, 0);
    c11 = __builtin_amdgcn_mfma_f32_16x16x32_bf16(A1h, B1l, c11, 0, 0, 0);
    c00 = __builtin_amdgcn_mfma_f32_16x16x32_bf16(A0l, B0h, c00, 0, 0, 0);
    c01 = __builtin_amdgcn_mfma_f32_16x16x32_bf16(A0l, B1h, c01, 0, 0, 0);
    c10 = __builtin_amdgcn_mfma_f32_16x16x32_bf16(A1l, B0h, c10, 0, 0, 0);
    c11 = __builtin_amdgcn_mfma_f32_16x16x32_bf16(A1l, B1h, c11, 0, 0, 0);
  }

  int orow = (lane >> 4) << 2;
  int col0 = n0 + lr, col1 = n0 + 16 + lr;
  #pragma unroll
  for (int r = 0; r < 4; r++) {
    int row0 = i0 + orow + r, row1 = row0 + 16;
    psum[(((size_t)z*LQ + row0)*NH + h)*64 + col0] = c00[r];
    psum[(((size_t)z*LQ + row0)*NH + h)*64 + col1] = c01[r];
    psum[(((size_t)z*LQ + row1)*NH + h)*64 + col0] = c10[r];
    psum[(((size_t)z*LQ + row1)*NH + h)*64 + col1] = c11[r];
  }
}

// ---------------------------------------------------------------- fused av_reduce + pts_feat -> comb (split-bf16)
__global__ void k_avpts(const float* __restrict__ psum, const float* __restrict__ rot,
                        const float* __restrict__ trans,
                        u16* __restrict__ combh, u16* __restrict__ combl) {
  int idx = blockIdx.x * 256 + threadIdx.x;
  if (idx >= LQ*NH*40) return;
  int w = idx % 40; int ih = idx / 40; int h = ih % NH; int i = ih / NH;
  size_t base = ((size_t)i*NH + h)*64;
  u16 h_, l_;
  if (w < 32) {
    float s = 0.f;
    for (int z = 0; z < 4; z++) s += psum[(size_t)z*LQ*NH*64 + base + w];
    split_bf16(s, h_, l_);
    combh[(size_t)i*2304 + h*32 + w] = h_;
    combl[(size_t)i*2304 + h*32 + w] = l_;
  } else {
    int p = w - 32;
    float g[3];
    #pragma unroll
    for (int r = 0; r < 3; r++) {
      int n = 32 + p*3 + r;
      float s = 0.f;
      for (int z = 0; z < 4; z++) s += psum[(size_t)z*LQ*NH*64 + base + n];
      g[r] = s;
    }
    const float* R = rot + (size_t)i*9;
    const float* tr = trans + (size_t)i*3;
    float x = g[0]-tr[0], y = g[1]-tr[1], z = g[2]-tr[2];
    float lx = fmaf(R[0],x, fmaf(R[3],y, R[6]*z));
    float ly = fmaf(R[1],x, fmaf(R[4],y, R[7]*z));
    float lz = fmaf(R[2],x, fmaf(R[5],y, R[8]*z));
    float nrm = sqrtf(fmaf(lx,lx, fmaf(ly,ly, lz*lz)));
    size_t dst = (size_t)i*2304 + 384 + (h*8 + p)*4;
    split_bf16(nrm, h_, l_); combh[dst+0] = h_; combl[dst+0] = l_;
    split_bf16(lx,  h_, l_); combh[dst+1] = h_; combl[dst+1] = l_;
    split_bf16(ly,  h_, l_); combh[dst+2] = h_; combl[dst+2] = l_;
    split_bf16(lz,  h_, l_); combh[dst+3] = h_; combl[dst+3] = l_;
  }
}

// ================================================================ launcher
extern "C" void kernel_launch(void* const* d_in, const int* in_sizes, int n_in,
                              void* d_out, int out_size, void* d_ws, size_t ws_size,
                              hipStream_t stream) {
  const float* single = (const float*)d_in[0];
  const float* pair   = (const float*)d_in[1];
  const float* rot    = (const float*)d_in[2];
  const float* trans  = (const float*)d_in[3];
  const float* mask   = (const float*)d_in[4];
  const float* ln_w   = (const float*)d_in[5];
  const float* ln_b   = (const float*)d_in[6];
  const float* Wq     = (const float*)d_in[7];
  const float* bq     = (const float*)d_in[8];
  const float* Wk     = (const float*)d_in[9];
  const float* bk     = (const float*)d_in[10];
  const float* Wv     = (const float*)d_in[11];
  const float* bv     = (const float*)d_in[12];
  const float* Wqp    = (const float*)d_in[13];
  const float* bqp    = (const float*)d_in[14];
  const float* Wkp    = (const float*)d_in[15];
  const float* bkp    = (const float*)d_in[16];
  const float* Wvp    = (const float*)d_in[17];
  const float* bvp    = (const float*)d_in[18];
  const float* Wpb    = (const float*)d_in[19];
  const float* bpb    = (const float*)d_in[20];
  const float* Wo     = (const float*)d_in[21];
  const float* bo     = (const float*)d_in[22];
  const float* w_c    = (const float*)d_in[23];
  const float* w_l    = (const float*)d_in[24];
  const float* gamma  = (const float*)d_in[25];
  float* out = (float*)d_out;

  float* p = (float*)d_ws;
  auto alloc = [&](size_t n) { float* r = p; p += n; return r; };
  u16* WcatTh = (u16*)alloc((size_t)NPP*DS/2);
  u16* WcatTl = (u16*)alloc((size_t)NPP*DS/2);
  u16* snh    = (u16*)alloc((size_t)LQ*DS/2);
  u16* snl    = (u16*)alloc((size_t)LQ*DS/2);
  u16* WoTh   = (u16*)alloc((size_t)DS*2304/2);
  u16* WoTl   = (u16*)alloc((size_t)DS*2304/2);
  u16* combh  = (u16*)alloc((size_t)LQ*2304/2);
  u16* combl  = (u16*)alloc((size_t)LQ*2304/2);
  u16* Vth    = (u16*)alloc((size_t)NH*64*LQ/2);
  u16* Vtl    = (u16*)alloc((size_t)NH*64*LQ/2);
  u16* Awh    = (u16*)alloc((size_t)NH*LQ*LQ/2);
  u16* Awl    = (u16*)alloc((size_t)NH*LQ*LQ/2);
  float* bcat    = alloc(NPP);
  float* WpbT    = alloc((size_t)NH*DPAIR);
  float* C1      = alloc((size_t)LQ*NPP);
  float* S       = alloc((size_t)NH*LQ*LQ);
  float* pairpart= alloc((size_t)LQ*NC*NH*DPAIR);
  float* msum    = alloc((size_t)LQ*NC*NH*2);
  float* psum    = alloc((size_t)4*LQ*NH*64);
  float* outpart = alloc((size_t)8*LQ*DS);

  k_prep<<<dim3(897), 256, 0, stream>>>(
      Wq, Wk, Wv, Wqp, Wkp, Wvp, bq, bk, bv, bqp, bkp, bvp, Wpb, Wo,
      single, ln_w, ln_b, WcatTh, WcatTl, bcat, WpbT, WoTh, WoTl, snh, snl);
  k_gemm_mfma<<<dim3(NPP/64, LQ/64, 1), 256, 0, stream>>>(
      snh, snl, WcatTh, WcatTl, bcat, C1, nullptr, LQ, NPP, DS);
  k_feat_logits<<<dim3(LQ/64, LQ/64, NH), 256, 0, stream>>>(
      C1, rot, trans, gamma, w_c, w_l, S);
  k_vt<<<dim3(NH, LQ/256), 256, 0, stream>>>(C1, rot, trans, Vth, Vtl);
  k_pair_chunk<<<dim3(LQ, NC), 256, 0, stream>>>(
      pair, WpbT, bpb, mask, S, pairpart, msum);
  k_scs_pairout<<<dim3(LQ), 384, 0, stream>>>(
      msum, pairpart, S, Awh, Awl, combh, combl);
  k_attn_mfma<<<dim3(4, LQ/64, NH), 256, 0, stream>>>(
      Awh, Awl, Vth, Vtl, psum);
  k_avpts<<<dim3((LQ*NH*40 + 255)/256), 256, 0, stream>>>(
      psum, rot, trans, combh, combl);
  k_gemm_mfma<<<dim3(DS/64, LQ/64, 8), 256, 0, stream>>>(
      combh, combl, WoTh, WoTl, nullptr, nullptr, outpart, LQ, DS, 2304);
  k_reduce_bias<<<dim3((LQ*DS + 255)/256), 256, 0, stream>>>(outpart, bo, out, LQ*DS, DS, 8);
}